// Round 1
// baseline (3063.909 us; speedup 1.0000x reference)
//
#include <hip/hip_runtime.h>

static constexpr float BN_EPS = 1e-5f;

__device__ __forceinline__ void fatomic_add(float* p, float v) {
  unsafeAtomicAdd(p, v);  // HW global_atomic_add_f32
}

__global__ void k_fill1(float* __restrict__ p, int n) {
  int i = blockIdx.x * 256 + threadIdx.x;
  if (i < n) p[i] = 1.0f;
}

__global__ void k_deg(const int* __restrict__ col, const float* __restrict__ ew,
                      float* __restrict__ deg, int e) {
  int i = blockIdx.x * 256 + threadIdx.x;
  if (i < e) fatomic_add(&deg[col[i]], ew[i]);
}

__global__ void k_rsqrt(float* __restrict__ p, int n) {
  int i = blockIdx.x * 256 + threadIdx.x;
  if (i < n) p[i] = rsqrtf(p[i]);
}

__global__ void k_norm(const int* __restrict__ row, const int* __restrict__ col,
                       const float* __restrict__ ew, const float* __restrict__ dis,
                       float* __restrict__ nrm, int e) {
  int i = blockIdx.x * 256 + threadIdx.x;
  if (i < e) nrm[i] = dis[row[i]] * ew[i] * dis[col[i]];
}

// Tiled fp32 GEMM: [n,K] @ [K,64]. Block = 256 threads = 64 rows x 4 col-segments
// of 16 outputs each. Weights staged in LDS (row-major [K][64] as float4).
// DUAL also computes x@Wb + bb (shares the x loads) for the residual projection.
template <int K, bool DUAL>
__global__ __launch_bounds__(256) void k_gemm(
    const float* __restrict__ x, const float* __restrict__ Wa,
    float* __restrict__ outa, const float* __restrict__ Wb,
    const float* __restrict__ bb, float* __restrict__ outb, int n) {
  __shared__ float4 wA[K * 16];
  __shared__ float4 wB[DUAL ? K * 16 : 1];
  int tid = threadIdx.x;
  for (int i = tid; i < K * 16; i += 256) wA[i] = ((const float4*)Wa)[i];
  if (DUAL)
    for (int i = tid; i < K * 16; i += 256) wB[i] = ((const float4*)Wb)[i];
  __syncthreads();

  int r = tid >> 2, cseg = tid & 3;
  int rowi = blockIdx.x * 64 + r;
  if (rowi >= n) return;

  float acc1[16];
  float acc2[16];
#pragma unroll
  for (int j = 0; j < 16; j++) { acc1[j] = 0.f; acc2[j] = 0.f; }

  const float4* xr = (const float4*)(x + (size_t)rowi * K);
#pragma unroll 2
  for (int k4 = 0; k4 < K / 4; k4++) {
    float4 a = xr[k4];
#pragma unroll
    for (int u = 0; u < 4; u++) {
      float ak = (u == 0) ? a.x : (u == 1) ? a.y : (u == 2) ? a.z : a.w;
      int k = k4 * 4 + u;
      const float4* wr = &wA[k * 16 + cseg * 4];
#pragma unroll
      for (int q = 0; q < 4; q++) {
        float4 w = wr[q];
        acc1[q * 4 + 0] = fmaf(ak, w.x, acc1[q * 4 + 0]);
        acc1[q * 4 + 1] = fmaf(ak, w.y, acc1[q * 4 + 1]);
        acc1[q * 4 + 2] = fmaf(ak, w.z, acc1[q * 4 + 2]);
        acc1[q * 4 + 3] = fmaf(ak, w.w, acc1[q * 4 + 3]);
      }
      if (DUAL) {
        const float4* wr2 = &wB[k * 16 + cseg * 4];
#pragma unroll
        for (int q = 0; q < 4; q++) {
          float4 w = wr2[q];
          acc2[q * 4 + 0] = fmaf(ak, w.x, acc2[q * 4 + 0]);
          acc2[q * 4 + 1] = fmaf(ak, w.y, acc2[q * 4 + 1]);
          acc2[q * 4 + 2] = fmaf(ak, w.z, acc2[q * 4 + 2]);
          acc2[q * 4 + 3] = fmaf(ak, w.w, acc2[q * 4 + 3]);
        }
      }
    }
  }

  float* o1 = outa + (size_t)rowi * 64 + cseg * 16;
#pragma unroll
  for (int q = 0; q < 4; q++)
    ((float4*)o1)[q] =
        make_float4(acc1[q * 4 + 0], acc1[q * 4 + 1], acc1[q * 4 + 2], acc1[q * 4 + 3]);
  if (DUAL) {
    float* o2 = outb + (size_t)rowi * 64 + cseg * 16;
#pragma unroll
    for (int q = 0; q < 4; q++) {
      float4 bv = ((const float4*)bb)[cseg * 4 + q];
      ((float4*)o2)[q] = make_float4(acc2[q * 4 + 0] + bv.x, acc2[q * 4 + 1] + bv.y,
                                     acc2[q * 4 + 2] + bv.z, acc2[q * 4 + 3] + bv.w);
    }
  }
}

// One (edge-or-selfloop, 4-channel chunk) per thread: 16 threads cooperate on an
// entry's 64 channels. Gather hw[row], scale by norm, atomic-scatter to agg[col].
__global__ __launch_bounds__(256) void k_scatter(
    const int* __restrict__ row, const int* __restrict__ col,
    const float* __restrict__ nrm, const float* __restrict__ dis,
    const float* __restrict__ hw, float* __restrict__ agg, int e, int n) {
  int gid = blockIdx.x * 256 + threadIdx.x;
  int entry = gid >> 4;
  if (entry >= e + n) return;
  int c4 = (gid & 15) * 4;
  int r, c;
  float w;
  if (entry < e) {
    r = row[entry];
    c = col[entry];
    w = nrm[entry];
  } else {
    r = entry - e;  // self-loop: norm = dis[i]^2
    c = r;
    float d = dis[r];
    w = d * d;
  }
  float4 v = *(const float4*)(hw + (size_t)r * 64 + c4);
  float* dst = agg + (size_t)c * 64 + c4;
  fatomic_add(dst + 0, v.x * w);
  fatomic_add(dst + 1, v.y * w);
  fatomic_add(dst + 2, v.z * w);
  fatomic_add(dst + 3, v.w * w);
}

// Per-channel sum and sum-of-squares over nodes -> stats[0..63]=sum, [64..127]=sumsq.
__global__ __launch_bounds__(256) void k_stats(const float* __restrict__ agg,
                                               float* __restrict__ stats, int n) {
  int c = threadIdx.x & 63;
  int lr = threadIdx.x >> 6;  // 0..3
  float s = 0.f, s2 = 0.f;
  for (int i = blockIdx.x * 4 + lr; i < n; i += gridDim.x * 4) {
    float v = agg[(size_t)i * 64 + c];
    s += v;
    s2 += v * v;
  }
  __shared__ float red[4][64];
  __shared__ float red2[4][64];
  red[lr][c] = s;
  red2[lr][c] = s2;
  __syncthreads();
  if (threadIdx.x < 64) {
    float ts = red[0][c] + red[1][c] + red[2][c] + red[3][c];
    float t2 = red2[0][c] + red2[1][c] + red2[2][c] + red2[3][c];
    fatomic_add(&stats[c], ts);
    fatomic_add(&stats[64 + c], t2);
  }
}

// out = relu(g*(agg-mu)*rsqrt(var+eps)+beta) + res   (bias b cancels through BN)
__global__ __launch_bounds__(256) void k_bnrelu(
    const float* __restrict__ agg, const float* __restrict__ res,
    const float* __restrict__ stats, const float* __restrict__ g,
    const float* __restrict__ beta, float* __restrict__ out, int n) {
  int idx = blockIdx.x * 256 + threadIdx.x;
  if (idx >= n * 16) return;
  int c4 = (idx & 15) * 4;
  float invN = 1.0f / (float)n;
  float4 a = ((const float4*)agg)[idx];
  float4 rr = ((const float4*)res)[idx];
  float av[4] = {a.x, a.y, a.z, a.w};
  float rv[4] = {rr.x, rr.y, rr.z, rr.w};
  float vo[4];
#pragma unroll
  for (int j = 0; j < 4; j++) {
    int c = c4 + j;
    float mu = stats[c] * invN;
    float var = stats[64 + c] * invN - mu * mu;
    float sc = g[c] * rsqrtf(var + BN_EPS);
    float v = (av[j] - mu) * sc + beta[c];
    vo[j] = fmaxf(v, 0.0f) + rv[j];
  }
  ((float4*)out)[idx] = make_float4(vo[0], vo[1], vo[2], vo[3]);
}

extern "C" void kernel_launch(void* const* d_in, const int* in_sizes, int n_in,
                              void* d_out, int out_size, void* d_ws, size_t ws_size,
                              hipStream_t stream) {
  const float* x = (const float*)d_in[0];
  const int* ei = (const int*)d_in[1];
  const float* ew = (const float*)d_in[2];
  const float* W1 = (const float*)d_in[3];
  // d_in[4] = b1: cancels through BN, unused
  const float* g1 = (const float*)d_in[5];
  const float* be1 = (const float*)d_in[6];
  const float* W2 = (const float*)d_in[7];
  // d_in[8] = b2: cancels through BN, unused
  const float* g2 = (const float*)d_in[9];
  const float* be2 = (const float*)d_in[10];
  const float* pW = (const float*)d_in[11];
  const float* pb = (const float*)d_in[12];

  int n = in_sizes[0] / 128;
  int e = in_sizes[1] / 2;
  const int* row = ei;      // source
  const int* col = ei + e;  // target

  float* ws = (float*)d_ws;
  float* dis = ws;                      // n
  float* nrm = dis + n;                 // e
  float* bufA = nrm + e;                // n*64  (hw1, then h)
  float* bufR = bufA + (size_t)n * 64;  // n*64  (residual, then hw2)
  float* bufB = bufR + (size_t)n * 64;  // n*64  (agg)
  float* stats = bufB + (size_t)n * 64; // 128

  float* out = (float*)d_out;

  int nb_n = (n + 255) / 256;
  int nb_e = (e + 255) / 256;
  int nb_g = (n + 63) / 64;
  int nb_s = ((e + n) * 16 + 255) / 256;
  int nb_b = (n * 16 + 255) / 256;
  size_t aggBytes = (size_t)n * 64 * sizeof(float);

  // gcn_norm
  k_fill1<<<nb_n, 256, 0, stream>>>(dis, n);  // self-loop weight 1 per node
  k_deg<<<nb_e, 256, 0, stream>>>(col, ew, dis, e);
  k_rsqrt<<<nb_n, 256, 0, stream>>>(dis, n);
  k_norm<<<nb_e, 256, 0, stream>>>(row, col, ew, dis, nrm, e);

  // layer 1: hw1 = x@W1 (bufA), residual = x@pW+pb (bufR)
  k_gemm<128, true><<<nb_g, 256, 0, stream>>>(x, W1, bufA, pW, pb, bufR, n);
  hipMemsetAsync(bufB, 0, aggBytes, stream);
  k_scatter<<<nb_s, 256, 0, stream>>>(row, col, nrm, dis, bufA, bufB, e, n);
  hipMemsetAsync(stats, 0, 128 * sizeof(float), stream);
  k_stats<<<1024, 256, 0, stream>>>(bufB, stats, n);
  k_bnrelu<<<nb_b, 256, 0, stream>>>(bufB, bufR, stats, g1, be1, bufA, n);  // h -> bufA

  // layer 2: hw2 = h@W2 (bufR)
  k_gemm<64, false><<<nb_g, 256, 0, stream>>>(bufA, W2, bufR, nullptr, nullptr, nullptr, n);
  hipMemsetAsync(bufB, 0, aggBytes, stream);
  k_scatter<<<nb_s, 256, 0, stream>>>(row, col, nrm, dis, bufR, bufB, e, n);
  hipMemsetAsync(stats, 0, 128 * sizeof(float), stream);
  k_stats<<<1024, 256, 0, stream>>>(bufB, stats, n);
  k_bnrelu<<<nb_b, 256, 0, stream>>>(bufB, bufA, stats, g2, be2, out, n);  // out = relu(bn)+h
}

// Round 2
// 1063.512 us; speedup vs baseline: 2.8809x; 2.8809x over previous
//
#include <hip/hip_runtime.h>

static constexpr float BN_EPS = 1e-5f;

__device__ __forceinline__ void fatomic_add(float* p, float v) {
  unsafeAtomicAdd(p, v);  // HW global_atomic_add_f32
}

__global__ void k_fill1(float* __restrict__ p, int n) {
  int i = blockIdx.x * 256 + threadIdx.x;
  if (i < n) p[i] = 1.0f;
}

__global__ void k_deg(const int* __restrict__ col, const float* __restrict__ ew,
                      float* __restrict__ deg, int e) {
  int i = blockIdx.x * 256 + threadIdx.x;
  if (i < e) fatomic_add(&deg[col[i]], ew[i]);
}

__global__ void k_rsqrt(float* __restrict__ p, int n) {
  int i = blockIdx.x * 256 + threadIdx.x;
  if (i < n) p[i] = rsqrtf(p[i]);
}

__global__ void k_norm(const int* __restrict__ row, const int* __restrict__ col,
                       const float* __restrict__ ew, const float* __restrict__ dis,
                       float* __restrict__ nrm, int e) {
  int i = blockIdx.x * 256 + threadIdx.x;
  if (i < e) nrm[i] = dis[row[i]] * ew[i] * dis[col[i]];
}

// ---- CSR build (keyed by target/col) ----
__global__ void k_hist(const int* __restrict__ col, int* __restrict__ cnt, int e) {
  int i = blockIdx.x * 256 + threadIdx.x;
  if (i < e) atomicAdd(&cnt[col[i]], 1);
}

// Single block, 1024 threads. In: cnt[n] (counts). Out: ptr[n+1] (exclusive
// prefix), and cnt[] overwritten with start offsets (cursor init).
__global__ __launch_bounds__(1024) void k_scan(int* __restrict__ cnt,
                                               int* __restrict__ ptr, int n) {
  __shared__ int part[1024];
  int t = threadIdx.x;
  int chunk = (n + 1023) >> 10;
  int b = t * chunk;
  int en = min(b + chunk, n);
  int s = 0;
  for (int i = b; i < en; i++) s += cnt[i];
  part[t] = s;
  __syncthreads();
  int v = s;
  for (int off = 1; off < 1024; off <<= 1) {
    int other = (t >= off) ? part[t - off] : 0;
    __syncthreads();
    v += other;
    part[t] = v;
    __syncthreads();
  }
  int run = v - s;  // exclusive prefix of this thread's chunk
  for (int i = b; i < en; i++) {
    int c = cnt[i];
    ptr[i] = run;
    cnt[i] = run;  // cursor init
    run += c;
  }
  if (t == 1023) ptr[n] = run;  // == e
}

__global__ void k_fillcsr(const int* __restrict__ row, const int* __restrict__ col,
                          const float* __restrict__ nrm, int* __restrict__ cursor,
                          int2* __restrict__ spair, int e) {
  int i = blockIdx.x * 256 + threadIdx.x;
  if (i >= e) return;
  int c = col[i];
  int p = atomicAdd(&cursor[c], 1);
  spair[p] = make_int2(row[i], __float_as_int(nrm[i]));
}

// ---- aggregation: one wave per node, lane = channel ----
__global__ __launch_bounds__(256) void k_agg(
    const int* __restrict__ ptr, const int2* __restrict__ spair,
    const float* __restrict__ dis, const float* __restrict__ hw,
    float* __restrict__ agg, int n) {
  int lane = threadIdx.x & 63;
  int wid = blockIdx.x * 4 + (threadIdx.x >> 6);
  int nw = gridDim.x * 4;
  for (int v = wid; v < n; v += nw) {
    float d = dis[v];
    float acc = d * d * hw[(size_t)v * 64 + lane];  // self-loop
    int beg = ptr[v], end = ptr[v + 1];
    if (beg < end) {
      int2 m = spair[beg];
      for (int j = beg + 1; j < end; j++) {
        int2 mn = spair[j];  // prefetch next edge meta
        acc = fmaf(__int_as_float(m.y), hw[(size_t)m.x * 64 + lane], acc);
        m = mn;
      }
      acc = fmaf(__int_as_float(m.y), hw[(size_t)m.x * 64 + lane], acc);
    }
    agg[(size_t)v * 64 + lane] = acc;
  }
}

// Tiled fp32 GEMM: [n,K] @ [K,64]. Block = 256 threads = 64 rows x 4 col-segments.
template <int K, bool DUAL>
__global__ __launch_bounds__(256) void k_gemm(
    const float* __restrict__ x, const float* __restrict__ Wa,
    float* __restrict__ outa, const float* __restrict__ Wb,
    const float* __restrict__ bb, float* __restrict__ outb, int n) {
  __shared__ float4 wA[K * 16];
  __shared__ float4 wB[DUAL ? K * 16 : 1];
  int tid = threadIdx.x;
  for (int i = tid; i < K * 16; i += 256) wA[i] = ((const float4*)Wa)[i];
  if (DUAL)
    for (int i = tid; i < K * 16; i += 256) wB[i] = ((const float4*)Wb)[i];
  __syncthreads();

  int r = tid >> 2, cseg = tid & 3;
  int rowi = blockIdx.x * 64 + r;
  if (rowi >= n) return;

  float acc1[16];
  float acc2[16];
#pragma unroll
  for (int j = 0; j < 16; j++) { acc1[j] = 0.f; acc2[j] = 0.f; }

  const float4* xr = (const float4*)(x + (size_t)rowi * K);
#pragma unroll 2
  for (int k4 = 0; k4 < K / 4; k4++) {
    float4 a = xr[k4];
#pragma unroll
    for (int u = 0; u < 4; u++) {
      float ak = (u == 0) ? a.x : (u == 1) ? a.y : (u == 2) ? a.z : a.w;
      int k = k4 * 4 + u;
      const float4* wr = &wA[k * 16 + cseg * 4];
#pragma unroll
      for (int q = 0; q < 4; q++) {
        float4 w = wr[q];
        acc1[q * 4 + 0] = fmaf(ak, w.x, acc1[q * 4 + 0]);
        acc1[q * 4 + 1] = fmaf(ak, w.y, acc1[q * 4 + 1]);
        acc1[q * 4 + 2] = fmaf(ak, w.z, acc1[q * 4 + 2]);
        acc1[q * 4 + 3] = fmaf(ak, w.w, acc1[q * 4 + 3]);
      }
      if (DUAL) {
        const float4* wr2 = &wB[k * 16 + cseg * 4];
#pragma unroll
        for (int q = 0; q < 4; q++) {
          float4 w = wr2[q];
          acc2[q * 4 + 0] = fmaf(ak, w.x, acc2[q * 4 + 0]);
          acc2[q * 4 + 1] = fmaf(ak, w.y, acc2[q * 4 + 1]);
          acc2[q * 4 + 2] = fmaf(ak, w.z, acc2[q * 4 + 2]);
          acc2[q * 4 + 3] = fmaf(ak, w.w, acc2[q * 4 + 3]);
        }
      }
    }
  }

  float* o1 = outa + (size_t)rowi * 64 + cseg * 16;
#pragma unroll
  for (int q = 0; q < 4; q++)
    ((float4*)o1)[q] =
        make_float4(acc1[q * 4 + 0], acc1[q * 4 + 1], acc1[q * 4 + 2], acc1[q * 4 + 3]);
  if (DUAL) {
    float* o2 = outb + (size_t)rowi * 64 + cseg * 16;
#pragma unroll
    for (int q = 0; q < 4; q++) {
      float4 bv = ((const float4*)bb)[cseg * 4 + q];
      ((float4*)o2)[q] = make_float4(acc2[q * 4 + 0] + bv.x, acc2[q * 4 + 1] + bv.y,
                                     acc2[q * 4 + 2] + bv.z, acc2[q * 4 + 3] + bv.w);
    }
  }
}

// Per-channel sum and sum-of-squares -> stats[0..63]=sum, [64..127]=sumsq.
__global__ __launch_bounds__(256) void k_stats(const float* __restrict__ agg,
                                               float* __restrict__ stats, int n) {
  int c = threadIdx.x & 63;
  int lr = threadIdx.x >> 6;
  float s = 0.f, s2 = 0.f;
  for (int i = blockIdx.x * 4 + lr; i < n; i += gridDim.x * 4) {
    float v = agg[(size_t)i * 64 + c];
    s += v;
    s2 += v * v;
  }
  __shared__ float red[4][64];
  __shared__ float red2[4][64];
  red[lr][c] = s;
  red2[lr][c] = s2;
  __syncthreads();
  if (threadIdx.x < 64) {
    float ts = red[0][c] + red[1][c] + red[2][c] + red[3][c];
    float t2 = red2[0][c] + red2[1][c] + red2[2][c] + red2[3][c];
    fatomic_add(&stats[c], ts);
    fatomic_add(&stats[64 + c], t2);
  }
}

// out = relu(g*(agg-mu)*rsqrt(var+eps)+beta) + res   (conv bias cancels in BN)
__global__ __launch_bounds__(256) void k_bnrelu(
    const float* __restrict__ agg, const float* __restrict__ res,
    const float* __restrict__ stats, const float* __restrict__ g,
    const float* __restrict__ beta, float* __restrict__ out, int n) {
  int idx = blockIdx.x * 256 + threadIdx.x;
  if (idx >= n * 16) return;
  int c4 = (idx & 15) * 4;
  float invN = 1.0f / (float)n;
  float4 a = ((const float4*)agg)[idx];
  float4 rr = ((const float4*)res)[idx];
  float av[4] = {a.x, a.y, a.z, a.w};
  float rv[4] = {rr.x, rr.y, rr.z, rr.w};
  float vo[4];
#pragma unroll
  for (int j = 0; j < 4; j++) {
    int c = c4 + j;
    float mu = stats[c] * invN;
    float var = stats[64 + c] * invN - mu * mu;
    float sc = g[c] * rsqrtf(var + BN_EPS);
    float v = (av[j] - mu) * sc + beta[c];
    vo[j] = fmaxf(v, 0.0f) + rv[j];
  }
  ((float4*)out)[idx] = make_float4(vo[0], vo[1], vo[2], vo[3]);
}

extern "C" void kernel_launch(void* const* d_in, const int* in_sizes, int n_in,
                              void* d_out, int out_size, void* d_ws, size_t ws_size,
                              hipStream_t stream) {
  const float* x = (const float*)d_in[0];
  const int* ei = (const int*)d_in[1];
  const float* ew = (const float*)d_in[2];
  const float* W1 = (const float*)d_in[3];
  const float* g1 = (const float*)d_in[5];
  const float* be1 = (const float*)d_in[6];
  const float* W2 = (const float*)d_in[7];
  const float* g2 = (const float*)d_in[9];
  const float* be2 = (const float*)d_in[10];
  const float* pW = (const float*)d_in[11];
  const float* pb = (const float*)d_in[12];

  int n = in_sizes[0] / 128;
  int e = in_sizes[1] / 2;
  const int* row = ei;      // source
  const int* col = ei + e;  // target

  // workspace layout (all region sizes multiples of 4 elements)
  float* ws = (float*)d_ws;
  float* dis = ws;                        // n
  float* nrm = dis + n;                   // e
  int* ptr = (int*)(nrm + e);             // n+4
  int* cursor = ptr + n + 4;              // n   (counts -> start offsets)
  int2* spair = (int2*)(cursor + n);      // e entries (2e ints)
  float* bufA = (float*)(spair + e);      // n*64
  float* bufR = bufA + (size_t)n * 64;    // n*64
  float* bufB = bufR + (size_t)n * 64;    // n*64
  float* stats = bufB + (size_t)n * 64;   // 128

  float* out = (float*)d_out;

  int nb_n = (n + 255) / 256;
  int nb_e = (e + 255) / 256;
  int nb_g = (n + 63) / 64;
  int nb_b = (n * 16 + 255) / 256;

  // gcn_norm
  k_fill1<<<nb_n, 256, 0, stream>>>(dis, n);
  k_deg<<<nb_e, 256, 0, stream>>>(col, ew, dis, e);
  k_rsqrt<<<nb_n, 256, 0, stream>>>(dis, n);
  k_norm<<<nb_e, 256, 0, stream>>>(row, col, ew, dis, nrm, e);

  // CSR build (by target node)
  hipMemsetAsync(cursor, 0, n * sizeof(int), stream);
  k_hist<<<nb_e, 256, 0, stream>>>(col, cursor, e);
  k_scan<<<1, 1024, 0, stream>>>(cursor, ptr, n);
  k_fillcsr<<<nb_e, 256, 0, stream>>>(row, col, nrm, cursor, spair, e);

  // layer 1
  k_gemm<128, true><<<nb_g, 256, 0, stream>>>(x, W1, bufA, pW, pb, bufR, n);
  k_agg<<<2048, 256, 0, stream>>>(ptr, spair, dis, bufA, bufB, n);
  hipMemsetAsync(stats, 0, 128 * sizeof(float), stream);
  k_stats<<<1024, 256, 0, stream>>>(bufB, stats, n);
  k_bnrelu<<<nb_b, 256, 0, stream>>>(bufB, bufR, stats, g1, be1, bufA, n);

  // layer 2
  k_gemm<64, false><<<nb_g, 256, 0, stream>>>(bufA, W2, bufR, nullptr, nullptr, nullptr, n);
  k_agg<<<2048, 256, 0, stream>>>(ptr, spair, dis, bufR, bufB, n);
  hipMemsetAsync(stats, 0, 128 * sizeof(float), stream);
  k_stats<<<1024, 256, 0, stream>>>(bufB, stats, n);
  k_bnrelu<<<nb_b, 256, 0, stream>>>(bufB, bufA, stats, g2, be2, out, n);
}

// Round 3
// 779.161 us; speedup vs baseline: 3.9323x; 1.3649x over previous
//
#include <hip/hip_runtime.h>

static constexpr float BN_EPS = 1e-5f;

__device__ __forceinline__ void fatomic_add(float* p, float v) {
  unsafeAtomicAdd(p, v);  // HW global_atomic_add_f32
}

__global__ void k_fill1(float* __restrict__ p, int n) {
  int i = blockIdx.x * 256 + threadIdx.x;
  if (i < n) p[i] = 1.0f;
}

// fused: weighted in-degree (float) + edge count histogram (int), both keyed by col
__global__ void k_deg_hist(const int* __restrict__ col, const float* __restrict__ ew,
                           float* __restrict__ deg, int* __restrict__ cnt, int e) {
  int i = blockIdx.x * 256 + threadIdx.x;
  if (i < e) {
    int c = col[i];
    fatomic_add(&deg[c], ew[i]);
    atomicAdd(&cnt[c], 1);
  }
}

__global__ void k_rsqrt(float* __restrict__ p, int n) {
  int i = blockIdx.x * 256 + threadIdx.x;
  if (i < n) p[i] = rsqrtf(p[i]);
}

// ---- device-wide exclusive scan of cnt[n] (1024 elems/block) ----
__global__ __launch_bounds__(256) void k_scan_part(const int* __restrict__ cnt,
                                                   int* __restrict__ bsum, int n) {
  __shared__ int sm[256];
  int t = threadIdx.x;
  int base = blockIdx.x * 1024 + t * 4;
  int s = 0;
#pragma unroll
  for (int j = 0; j < 4; j++) {
    int i = base + j;
    if (i < n) s += cnt[i];
  }
  sm[t] = s;
  __syncthreads();
  for (int off = 128; off > 0; off >>= 1) {
    if (t < off) sm[t] += sm[t + off];
    __syncthreads();
  }
  if (t == 0) bsum[blockIdx.x] = sm[0];
}

__global__ __launch_bounds__(1024) void k_scan_mid(int* __restrict__ bsum, int nb) {
  __shared__ int sm[1024];
  int t = threadIdx.x;
  int v = (t < nb) ? bsum[t] : 0;
  sm[t] = v;
  __syncthreads();
  for (int off = 1; off < 1024; off <<= 1) {
    int o = (t >= off) ? sm[t - off] : 0;
    __syncthreads();
    sm[t] += o;
    __syncthreads();
  }
  if (t < nb) bsum[t] = sm[t] - v;  // exclusive block offsets
}

__global__ __launch_bounds__(256) void k_scan_apply(int* __restrict__ cnt,
                                                    int* __restrict__ ptr,
                                                    const int* __restrict__ bsum,
                                                    int n, int e) {
  __shared__ int sm[256];
  int t = threadIdx.x;
  int base = blockIdx.x * 1024 + t * 4;
  int v[4];
  int s = 0;
#pragma unroll
  for (int j = 0; j < 4; j++) {
    int i = base + j;
    v[j] = (i < n) ? cnt[i] : 0;
    s += v[j];
  }
  sm[t] = s;
  __syncthreads();
  // inclusive Hillis-Steele over 256 thread-sums
  for (int off = 1; off < 256; off <<= 1) {
    int o = (t >= off) ? sm[t - off] : 0;
    __syncthreads();
    sm[t] += o;
    __syncthreads();
  }
  int run = bsum[blockIdx.x] + sm[t] - s;  // exclusive prefix for this thread
#pragma unroll
  for (int j = 0; j < 4; j++) {
    int i = base + j;
    if (i < n) {
      ptr[i] = run;
      cnt[i] = run;  // cursor init
      run += v[j];
    }
  }
  if (blockIdx.x == 0 && t == 0) ptr[n] = e;
}

// fill CSR entries; norm computed inline (nrm buffer eliminated)
__global__ void k_fillcsr(const int* __restrict__ row, const int* __restrict__ col,
                          const float* __restrict__ ew, const float* __restrict__ dis,
                          int* __restrict__ cursor, int2* __restrict__ spair, int e) {
  int i = blockIdx.x * 256 + threadIdx.x;
  if (i >= e) return;
  int r = row[i], c = col[i];
  float nr = dis[r] * ew[i] * dis[c];
  int p = atomicAdd(&cursor[c], 1);
  spair[p] = make_int2(r, __float_as_int(nr));
}

// ---- aggregation: one wave per node, lane = channel ----
__global__ __launch_bounds__(256) void k_agg(
    const int* __restrict__ ptr, const int2* __restrict__ spair,
    const float* __restrict__ dis, const float* __restrict__ hw,
    float* __restrict__ agg, int n) {
  int lane = threadIdx.x & 63;
  int wid = blockIdx.x * 4 + (threadIdx.x >> 6);
  int nw = gridDim.x * 4;
  for (int v = wid; v < n; v += nw) {
    float d = dis[v];
    float acc = d * d * hw[(size_t)v * 64 + lane];  // self-loop
    int beg = ptr[v], end = ptr[v + 1];
    if (beg < end) {
      int2 m = spair[beg];
      for (int j = beg + 1; j < end; j++) {
        int2 mn = spair[j];  // prefetch next edge meta
        acc = fmaf(__int_as_float(m.y), hw[(size_t)m.x * 64 + lane], acc);
        m = mn;
      }
      acc = fmaf(__int_as_float(m.y), hw[(size_t)m.x * 64 + lane], acc);
    }
    agg[(size_t)v * 64 + lane] = acc;
  }
}

// Tiled fp32 GEMM: [n,K] @ [K,64]. Block = 256 threads = 64 rows x 4 col-segments.
template <int K, bool DUAL>
__global__ __launch_bounds__(256) void k_gemm(
    const float* __restrict__ x, const float* __restrict__ Wa,
    float* __restrict__ outa, const float* __restrict__ Wb,
    const float* __restrict__ bb, float* __restrict__ outb, int n) {
  __shared__ float4 wA[K * 16];
  __shared__ float4 wB[DUAL ? K * 16 : 1];
  int tid = threadIdx.x;
  for (int i = tid; i < K * 16; i += 256) wA[i] = ((const float4*)Wa)[i];
  if (DUAL)
    for (int i = tid; i < K * 16; i += 256) wB[i] = ((const float4*)Wb)[i];
  __syncthreads();

  int r = tid >> 2, cseg = tid & 3;
  int rowi = blockIdx.x * 64 + r;
  if (rowi >= n) return;

  float acc1[16];
  float acc2[16];
#pragma unroll
  for (int j = 0; j < 16; j++) { acc1[j] = 0.f; acc2[j] = 0.f; }

  const float4* xr = (const float4*)(x + (size_t)rowi * K);
#pragma unroll 2
  for (int k4 = 0; k4 < K / 4; k4++) {
    float4 a = xr[k4];
#pragma unroll
    for (int u = 0; u < 4; u++) {
      float ak = (u == 0) ? a.x : (u == 1) ? a.y : (u == 2) ? a.z : a.w;
      int k = k4 * 4 + u;
      const float4* wr = &wA[k * 16 + cseg * 4];
#pragma unroll
      for (int q = 0; q < 4; q++) {
        float4 w = wr[q];
        acc1[q * 4 + 0] = fmaf(ak, w.x, acc1[q * 4 + 0]);
        acc1[q * 4 + 1] = fmaf(ak, w.y, acc1[q * 4 + 1]);
        acc1[q * 4 + 2] = fmaf(ak, w.z, acc1[q * 4 + 2]);
        acc1[q * 4 + 3] = fmaf(ak, w.w, acc1[q * 4 + 3]);
      }
      if (DUAL) {
        const float4* wr2 = &wB[k * 16 + cseg * 4];
#pragma unroll
        for (int q = 0; q < 4; q++) {
          float4 w = wr2[q];
          acc2[q * 4 + 0] = fmaf(ak, w.x, acc2[q * 4 + 0]);
          acc2[q * 4 + 1] = fmaf(ak, w.y, acc2[q * 4 + 1]);
          acc2[q * 4 + 2] = fmaf(ak, w.z, acc2[q * 4 + 2]);
          acc2[q * 4 + 3] = fmaf(ak, w.w, acc2[q * 4 + 3]);
        }
      }
    }
  }

  float* o1 = outa + (size_t)rowi * 64 + cseg * 16;
#pragma unroll
  for (int q = 0; q < 4; q++)
    ((float4*)o1)[q] =
        make_float4(acc1[q * 4 + 0], acc1[q * 4 + 1], acc1[q * 4 + 2], acc1[q * 4 + 3]);
  if (DUAL) {
    float* o2 = outb + (size_t)rowi * 64 + cseg * 16;
#pragma unroll
    for (int q = 0; q < 4; q++) {
      float4 bv = ((const float4*)bb)[cseg * 4 + q];
      ((float4*)o2)[q] = make_float4(acc2[q * 4 + 0] + bv.x, acc2[q * 4 + 1] + bv.y,
                                     acc2[q * 4 + 2] + bv.z, acc2[q * 4 + 3] + bv.w);
    }
  }
}

// Per-channel sum and sum-of-squares -> stats[0..63]=sum, [64..127]=sumsq.
__global__ __launch_bounds__(256) void k_stats(const float* __restrict__ agg,
                                               float* __restrict__ stats, int n) {
  int c = threadIdx.x & 63;
  int lr = threadIdx.x >> 6;
  float s = 0.f, s2 = 0.f;
  for (int i = blockIdx.x * 4 + lr; i < n; i += gridDim.x * 4) {
    float v = agg[(size_t)i * 64 + c];
    s += v;
    s2 += v * v;
  }
  __shared__ float red[4][64];
  __shared__ float red2[4][64];
  red[lr][c] = s;
  red2[lr][c] = s2;
  __syncthreads();
  if (threadIdx.x < 64) {
    float ts = red[0][c] + red[1][c] + red[2][c] + red[3][c];
    float t2 = red2[0][c] + red2[1][c] + red2[2][c] + red2[3][c];
    fatomic_add(&stats[c], ts);
    fatomic_add(&stats[64 + c], t2);
  }
}

// out = relu(g*(agg-mu)*rsqrt(var+eps)+beta) + res   (conv bias cancels in BN)
__global__ __launch_bounds__(256) void k_bnrelu(
    const float* __restrict__ agg, const float* __restrict__ res,
    const float* __restrict__ stats, const float* __restrict__ g,
    const float* __restrict__ beta, float* __restrict__ out, int n) {
  int idx = blockIdx.x * 256 + threadIdx.x;
  if (idx >= n * 16) return;
  int c4 = (idx & 15) * 4;
  float invN = 1.0f / (float)n;
  float4 a = ((const float4*)agg)[idx];
  float4 rr = ((const float4*)res)[idx];
  float av[4] = {a.x, a.y, a.z, a.w};
  float rv[4] = {rr.x, rr.y, rr.z, rr.w};
  float vo[4];
#pragma unroll
  for (int j = 0; j < 4; j++) {
    int c = c4 + j;
    float mu = stats[c] * invN;
    float var = stats[64 + c] * invN - mu * mu;
    float sc = g[c] * rsqrtf(var + BN_EPS);
    float v = (av[j] - mu) * sc + beta[c];
    vo[j] = fmaxf(v, 0.0f) + rv[j];
  }
  ((float4*)out)[idx] = make_float4(vo[0], vo[1], vo[2], vo[3]);
}

extern "C" void kernel_launch(void* const* d_in, const int* in_sizes, int n_in,
                              void* d_out, int out_size, void* d_ws, size_t ws_size,
                              hipStream_t stream) {
  const float* x = (const float*)d_in[0];
  const int* ei = (const int*)d_in[1];
  const float* ew = (const float*)d_in[2];
  const float* W1 = (const float*)d_in[3];
  const float* g1 = (const float*)d_in[5];
  const float* be1 = (const float*)d_in[6];
  const float* W2 = (const float*)d_in[7];
  const float* g2 = (const float*)d_in[9];
  const float* be2 = (const float*)d_in[10];
  const float* pW = (const float*)d_in[11];
  const float* pb = (const float*)d_in[12];

  int n = in_sizes[0] / 128;
  int e = in_sizes[1] / 2;
  const int* row = ei;      // source
  const int* col = ei + e;  // target

  // workspace layout
  float* ws = (float*)d_ws;
  float* dis = ws;                        // n
  int* ptr = (int*)(dis + n);             // n+4
  int* cursor = ptr + n + 4;              // n   (counts -> start offsets)
  int* bsum = cursor + n;                 // 1024
  int2* spair = (int2*)(bsum + 1024);     // e entries (2e ints)
  float* bufA = (float*)(spair + e);      // n*64
  float* bufR = bufA + (size_t)n * 64;    // n*64
  float* bufB = bufR + (size_t)n * 64;    // n*64
  float* stats = bufB + (size_t)n * 64;   // 128

  float* out = (float*)d_out;

  int nb_n = (n + 255) / 256;
  int nb_e = (e + 255) / 256;
  int nb_g = (n + 63) / 64;
  int nb_b = (n * 16 + 255) / 256;
  int nb_sc = (n + 1023) / 1024;  // scan blocks (1024 elems each), must be <= 1024

  // gcn_norm + CSR build
  k_fill1<<<nb_n, 256, 0, stream>>>(dis, n);
  hipMemsetAsync(cursor, 0, n * sizeof(int), stream);
  k_deg_hist<<<nb_e, 256, 0, stream>>>(col, ew, dis, cursor, e);
  k_rsqrt<<<nb_n, 256, 0, stream>>>(dis, n);
  k_scan_part<<<nb_sc, 256, 0, stream>>>(cursor, bsum, n);
  k_scan_mid<<<1, 1024, 0, stream>>>(bsum, nb_sc);
  k_scan_apply<<<nb_sc, 256, 0, stream>>>(cursor, ptr, bsum, n, e);
  k_fillcsr<<<nb_e, 256, 0, stream>>>(row, col, ew, dis, cursor, spair, e);

  // layer 1
  k_gemm<128, true><<<nb_g, 256, 0, stream>>>(x, W1, bufA, pW, pb, bufR, n);
  k_agg<<<2048, 256, 0, stream>>>(ptr, spair, dis, bufA, bufB, n);
  hipMemsetAsync(stats, 0, 128 * sizeof(float), stream);
  k_stats<<<1024, 256, 0, stream>>>(bufB, stats, n);
  k_bnrelu<<<nb_b, 256, 0, stream>>>(bufB, bufR, stats, g1, be1, bufA, n);

  // layer 2
  k_gemm<64, false><<<nb_g, 256, 0, stream>>>(bufA, W2, bufR, nullptr, nullptr, nullptr, n);
  k_agg<<<2048, 256, 0, stream>>>(ptr, spair, dis, bufR, bufB, n);
  hipMemsetAsync(stats, 0, 128 * sizeof(float), stream);
  k_stats<<<1024, 256, 0, stream>>>(bufB, stats, n);
  k_bnrelu<<<nb_b, 256, 0, stream>>>(bufB, bufA, stats, g2, be2, out, n);
}

// Round 4
// 659.270 us; speedup vs baseline: 4.6474x; 1.1819x over previous
//
#include <hip/hip_runtime.h>

static constexpr float BN_EPS = 1e-5f;
typedef unsigned int uint;
typedef unsigned short ushort;

__device__ __forceinline__ void fatomic_add(float* p, float v) {
  unsafeAtomicAdd(p, v);  // HW global_atomic_add_f32
}

__device__ __forceinline__ ushort f2bf(float f) {  // f32 -> bf16 RNE
  uint u = __float_as_uint(f);
  u += 0x7fffu + ((u >> 16) & 1u);
  return (ushort)(u >> 16);
}

__device__ __forceinline__ float4 bf4_decode(uint2 r) {
  return make_float4(__uint_as_float(r.x << 16), __uint_as_float(r.x & 0xffff0000u),
                     __uint_as_float(r.y << 16), __uint_as_float(r.y & 0xffff0000u));
}

__global__ void k_fill1(float* __restrict__ p, int n) {
  int i = blockIdx.x * 256 + threadIdx.x;
  if (i < n) p[i] = 1.0f;
}

// fused: weighted in-degree (float) + edge count histogram (int), both keyed by col
__global__ void k_deg_hist(const int* __restrict__ col, const float* __restrict__ ew,
                           float* __restrict__ deg, int* __restrict__ cnt, int e) {
  int i = blockIdx.x * 256 + threadIdx.x;
  if (i < e) {
    int c = col[i];
    fatomic_add(&deg[c], ew[i]);
    atomicAdd(&cnt[c], 1);
  }
}

__global__ void k_rsqrt(float* __restrict__ p, int n) {
  int i = blockIdx.x * 256 + threadIdx.x;
  if (i < n) p[i] = rsqrtf(p[i]);
}

// ---- device-wide exclusive scan of cnt[n] (1024 elems/block) ----
__global__ __launch_bounds__(256) void k_scan_part(const int* __restrict__ cnt,
                                                   int* __restrict__ bsum, int n) {
  __shared__ int sm[256];
  int t = threadIdx.x;
  int base = blockIdx.x * 1024 + t * 4;
  int s = 0;
#pragma unroll
  for (int j = 0; j < 4; j++) {
    int i = base + j;
    if (i < n) s += cnt[i];
  }
  sm[t] = s;
  __syncthreads();
  for (int off = 128; off > 0; off >>= 1) {
    if (t < off) sm[t] += sm[t + off];
    __syncthreads();
  }
  if (t == 0) bsum[blockIdx.x] = sm[0];
}

__global__ __launch_bounds__(1024) void k_scan_mid(int* __restrict__ bsum, int nb) {
  __shared__ int sm[1024];
  int t = threadIdx.x;
  int v = (t < nb) ? bsum[t] : 0;
  sm[t] = v;
  __syncthreads();
  for (int off = 1; off < 1024; off <<= 1) {
    int o = (t >= off) ? sm[t - off] : 0;
    __syncthreads();
    sm[t] += o;
    __syncthreads();
  }
  if (t < nb) bsum[t] = sm[t] - v;  // exclusive block offsets
}

__global__ __launch_bounds__(256) void k_scan_apply(int* __restrict__ cnt,
                                                    int* __restrict__ ptr,
                                                    const int* __restrict__ bsum,
                                                    int n, int e) {
  __shared__ int sm[256];
  int t = threadIdx.x;
  int base = blockIdx.x * 1024 + t * 4;
  int v[4];
  int s = 0;
#pragma unroll
  for (int j = 0; j < 4; j++) {
    int i = base + j;
    v[j] = (i < n) ? cnt[i] : 0;
    s += v[j];
  }
  sm[t] = s;
  __syncthreads();
  for (int off = 1; off < 256; off <<= 1) {
    int o = (t >= off) ? sm[t - off] : 0;
    __syncthreads();
    sm[t] += o;
    __syncthreads();
  }
  int run = bsum[blockIdx.x] + sm[t] - s;
#pragma unroll
  for (int j = 0; j < 4; j++) {
    int i = base + j;
    if (i < n) {
      ptr[i] = run;
      cnt[i] = run;  // cursor init
      run += v[j];
    }
  }
  if (blockIdx.x == 0 && t == 0) ptr[n] = e;
}

// fill CSR entries; norm computed inline
__global__ void k_fillcsr(const int* __restrict__ row, const int* __restrict__ col,
                          const float* __restrict__ ew, const float* __restrict__ dis,
                          int* __restrict__ cursor, int2* __restrict__ spair, int e) {
  int i = blockIdx.x * 256 + threadIdx.x;
  if (i >= e) return;
  int r = row[i], c = col[i];
  float nr = dis[r] * ew[i] * dis[c];
  int p = atomicAdd(&cursor[c], 1);
  spair[p] = make_int2(r, __float_as_int(nr));
}

// ---- aggregation: one wave per node; 4 edge-groups x 16 lanes (bf16x4/lane).
// Depth-2 software pipeline with metas issued 2 iterations ahead so in-order
// vmcnt waits never drain outstanding gathers.
__global__ __launch_bounds__(256) void k_agg(
    const int* __restrict__ ptr, const int2* __restrict__ spair,
    const float* __restrict__ dis, const ushort* __restrict__ hwb,
    float* __restrict__ agg, int n) {
  int lane = threadIdx.x & 63;
  int grp = lane >> 4;
  int li = lane & 15;
  int wid = blockIdx.x * 4 + (threadIdx.x >> 6);
  int nw = gridDim.x * 4;
  for (int v = wid; v < n; v += nw) {
    int beg = ptr[v], end = ptr[v + 1];
    float4 acc = make_float4(0.f, 0.f, 0.f, 0.f);
    if (grp == 0) {  // self-loop: norm = dis[v]^2
      float d = dis[v];
      uint2 rs = *(const uint2*)(hwb + (size_t)v * 64 + li * 4);
      float4 f = bf4_decode(rs);
      float w = d * d;
      acc = make_float4(w * f.x, w * f.y, w * f.z, w * f.w);
    }
    int j = beg + grp;
    if (j < end) {
      int2 m0 = spair[j];
      int2 m1 = (j + 4 < end) ? spair[j + 4] : m0;
      uint2 r0 = *(const uint2*)(hwb + (size_t)m0.x * 64 + li * 4);
      float w0 = __int_as_float(m0.y);
      while (j + 4 < end) {
        int2 m2 = (j + 8 < end) ? spair[j + 8] : m1;
        uint2 r1 = *(const uint2*)(hwb + (size_t)m1.x * 64 + li * 4);
        float w1 = __int_as_float(m1.y);
        float4 f = bf4_decode(r0);
        acc.x = fmaf(w0, f.x, acc.x);
        acc.y = fmaf(w0, f.y, acc.y);
        acc.z = fmaf(w0, f.z, acc.z);
        acc.w = fmaf(w0, f.w, acc.w);
        w0 = w1;
        r0 = r1;
        m1 = m2;
        j += 4;
      }
      float4 f = bf4_decode(r0);
      acc.x = fmaf(w0, f.x, acc.x);
      acc.y = fmaf(w0, f.y, acc.y);
      acc.z = fmaf(w0, f.z, acc.z);
      acc.w = fmaf(w0, f.w, acc.w);
    }
    // reduce across the 4 groups
    acc.x += __shfl_xor(acc.x, 16);
    acc.y += __shfl_xor(acc.y, 16);
    acc.z += __shfl_xor(acc.z, 16);
    acc.w += __shfl_xor(acc.w, 16);
    acc.x += __shfl_xor(acc.x, 32);
    acc.y += __shfl_xor(acc.y, 32);
    acc.z += __shfl_xor(acc.z, 32);
    acc.w += __shfl_xor(acc.w, 32);
    if (grp == 0) *(float4*)(agg + (size_t)v * 64 + li * 4) = acc;
  }
}

// Tiled fp32 GEMM: [n,K] @ [K,64] -> bf16 hw. Block = 256 = 64 rows x 4 col-segs.
// DUAL also writes x@Wb + bb as f32 (residual).
template <int K, bool DUAL>
__global__ __launch_bounds__(256) void k_gemm(
    const float* __restrict__ x, const float* __restrict__ Wa,
    ushort* __restrict__ outa, const float* __restrict__ Wb,
    const float* __restrict__ bb, float* __restrict__ outb, int n) {
  __shared__ float4 wA[K * 16];
  __shared__ float4 wB[DUAL ? K * 16 : 1];
  int tid = threadIdx.x;
  for (int i = tid; i < K * 16; i += 256) wA[i] = ((const float4*)Wa)[i];
  if (DUAL)
    for (int i = tid; i < K * 16; i += 256) wB[i] = ((const float4*)Wb)[i];
  __syncthreads();

  int r = tid >> 2, cseg = tid & 3;
  int rowi = blockIdx.x * 64 + r;
  if (rowi >= n) return;

  float acc1[16];
  float acc2[16];
#pragma unroll
  for (int j = 0; j < 16; j++) { acc1[j] = 0.f; acc2[j] = 0.f; }

  const float4* xr = (const float4*)(x + (size_t)rowi * K);
#pragma unroll 2
  for (int k4 = 0; k4 < K / 4; k4++) {
    float4 a = xr[k4];
#pragma unroll
    for (int u = 0; u < 4; u++) {
      float ak = (u == 0) ? a.x : (u == 1) ? a.y : (u == 2) ? a.z : a.w;
      int k = k4 * 4 + u;
      const float4* wr = &wA[k * 16 + cseg * 4];
#pragma unroll
      for (int q = 0; q < 4; q++) {
        float4 w = wr[q];
        acc1[q * 4 + 0] = fmaf(ak, w.x, acc1[q * 4 + 0]);
        acc1[q * 4 + 1] = fmaf(ak, w.y, acc1[q * 4 + 1]);
        acc1[q * 4 + 2] = fmaf(ak, w.z, acc1[q * 4 + 2]);
        acc1[q * 4 + 3] = fmaf(ak, w.w, acc1[q * 4 + 3]);
      }
      if (DUAL) {
        const float4* wr2 = &wB[k * 16 + cseg * 4];
#pragma unroll
        for (int q = 0; q < 4; q++) {
          float4 w = wr2[q];
          acc2[q * 4 + 0] = fmaf(ak, w.x, acc2[q * 4 + 0]);
          acc2[q * 4 + 1] = fmaf(ak, w.y, acc2[q * 4 + 1]);
          acc2[q * 4 + 2] = fmaf(ak, w.z, acc2[q * 4 + 2]);
          acc2[q * 4 + 3] = fmaf(ak, w.w, acc2[q * 4 + 3]);
        }
      }
    }
  }

  ushort* o1 = outa + (size_t)rowi * 64 + cseg * 16;
  uint pk[8];
#pragma unroll
  for (int q = 0; q < 8; q++)
    pk[q] = (uint)f2bf(acc1[2 * q]) | ((uint)f2bf(acc1[2 * q + 1]) << 16);
  ((uint4*)o1)[0] = make_uint4(pk[0], pk[1], pk[2], pk[3]);
  ((uint4*)o1)[1] = make_uint4(pk[4], pk[5], pk[6], pk[7]);

  if (DUAL) {
    float* o2 = outb + (size_t)rowi * 64 + cseg * 16;
#pragma unroll
    for (int q = 0; q < 4; q++) {
      float4 bv = ((const float4*)bb)[cseg * 4 + q];
      ((float4*)o2)[q] = make_float4(acc2[q * 4 + 0] + bv.x, acc2[q * 4 + 1] + bv.y,
                                     acc2[q * 4 + 2] + bv.z, acc2[q * 4 + 3] + bv.w);
    }
  }
}

// Per-channel sum and sum-of-squares -> stats[0..63]=sum, [64..127]=sumsq.
__global__ __launch_bounds__(256) void k_stats(const float* __restrict__ agg,
                                               float* __restrict__ stats, int n) {
  int c = threadIdx.x & 63;
  int lr = threadIdx.x >> 6;
  float s = 0.f, s2 = 0.f;
  for (int i = blockIdx.x * 4 + lr; i < n; i += gridDim.x * 4) {
    float v = agg[(size_t)i * 64 + c];
    s += v;
    s2 += v * v;
  }
  __shared__ float red[4][64];
  __shared__ float red2[4][64];
  red[lr][c] = s;
  red2[lr][c] = s2;
  __syncthreads();
  if (threadIdx.x < 64) {
    float ts = red[0][c] + red[1][c] + red[2][c] + red[3][c];
    float t2 = red2[0][c] + red2[1][c] + red2[2][c] + red2[3][c];
    fatomic_add(&stats[c], ts);
    fatomic_add(&stats[64 + c], t2);
  }
}

// out = relu(g*(agg-mu)*rsqrt(var+eps)+beta) + res   (conv bias cancels in BN)
__global__ __launch_bounds__(256) void k_bnrelu(
    const float* __restrict__ agg, const float* __restrict__ res,
    const float* __restrict__ stats, const float* __restrict__ g,
    const float* __restrict__ beta, float* __restrict__ out, int n) {
  int idx = blockIdx.x * 256 + threadIdx.x;
  if (idx >= n * 16) return;
  int c4 = (idx & 15) * 4;
  float invN = 1.0f / (float)n;
  float4 a = ((const float4*)agg)[idx];
  float4 rr = ((const float4*)res)[idx];
  float av[4] = {a.x, a.y, a.z, a.w};
  float rv[4] = {rr.x, rr.y, rr.z, rr.w};
  float vo[4];
#pragma unroll
  for (int j = 0; j < 4; j++) {
    int c = c4 + j;
    float mu = stats[c] * invN;
    float var = stats[64 + c] * invN - mu * mu;
    float sc = g[c] * rsqrtf(var + BN_EPS);
    float v = (av[j] - mu) * sc + beta[c];
    vo[j] = fmaxf(v, 0.0f) + rv[j];
  }
  ((float4*)out)[idx] = make_float4(vo[0], vo[1], vo[2], vo[3]);
}

extern "C" void kernel_launch(void* const* d_in, const int* in_sizes, int n_in,
                              void* d_out, int out_size, void* d_ws, size_t ws_size,
                              hipStream_t stream) {
  const float* x = (const float*)d_in[0];
  const int* ei = (const int*)d_in[1];
  const float* ew = (const float*)d_in[2];
  const float* W1 = (const float*)d_in[3];
  const float* g1 = (const float*)d_in[5];
  const float* be1 = (const float*)d_in[6];
  const float* W2 = (const float*)d_in[7];
  const float* g2 = (const float*)d_in[9];
  const float* be2 = (const float*)d_in[10];
  const float* pW = (const float*)d_in[11];
  const float* pb = (const float*)d_in[12];

  int n = in_sizes[0] / 128;
  int e = in_sizes[1] / 2;
  const int* row = ei;      // source
  const int* col = ei + e;  // target

  // workspace layout
  float* ws = (float*)d_ws;
  float* dis = ws;                             // n
  int* ptr = (int*)(dis + n);                  // n+4
  int* cursor = ptr + n + 4;                   // n
  int* bsum = cursor + n;                      // 1024
  int2* spair = (int2*)(bsum + 1024);          // e int2
  ushort* hwb = (ushort*)(spair + e);          // n*64 bf16 (hw1, then hw2)
  float* bufR = (float*)(hwb + (size_t)n * 64);  // n*64 (residual)
  float* bufB = bufR + (size_t)n * 64;         // n*64 (agg)
  float* bufA = bufB + (size_t)n * 64;         // n*64 (h)
  float* stats = bufA + (size_t)n * 64;        // 128

  float* out = (float*)d_out;

  int nb_n = (n + 255) / 256;
  int nb_e = (e + 255) / 256;
  int nb_g = (n + 63) / 64;
  int nb_b = (n * 16 + 255) / 256;
  int nb_sc = (n + 1023) / 1024;

  // gcn_norm + CSR build
  k_fill1<<<nb_n, 256, 0, stream>>>(dis, n);
  hipMemsetAsync(cursor, 0, n * sizeof(int), stream);
  k_deg_hist<<<nb_e, 256, 0, stream>>>(col, ew, dis, cursor, e);
  k_rsqrt<<<nb_n, 256, 0, stream>>>(dis, n);
  k_scan_part<<<nb_sc, 256, 0, stream>>>(cursor, bsum, n);
  k_scan_mid<<<1, 1024, 0, stream>>>(bsum, nb_sc);
  k_scan_apply<<<nb_sc, 256, 0, stream>>>(cursor, ptr, bsum, n, e);
  k_fillcsr<<<nb_e, 256, 0, stream>>>(row, col, ew, dis, cursor, spair, e);

  // layer 1
  k_gemm<128, true><<<nb_g, 256, 0, stream>>>(x, W1, hwb, pW, pb, bufR, n);
  k_agg<<<2048, 256, 0, stream>>>(ptr, spair, dis, hwb, bufB, n);
  hipMemsetAsync(stats, 0, 128 * sizeof(float), stream);
  k_stats<<<1024, 256, 0, stream>>>(bufB, stats, n);
  k_bnrelu<<<nb_b, 256, 0, stream>>>(bufB, bufR, stats, g1, be1, bufA, n);

  // layer 2
  k_gemm<64, false><<<nb_g, 256, 0, stream>>>(bufA, W2, hwb, nullptr, nullptr, nullptr, n);
  k_agg<<<2048, 256, 0, stream>>>(ptr, spair, dis, hwb, bufB, n);
  hipMemsetAsync(stats, 0, 128 * sizeof(float), stream);
  k_stats<<<1024, 256, 0, stream>>>(bufB, stats, n);
  k_bnrelu<<<nb_b, 256, 0, stream>>>(bufB, bufA, stats, g2, be2, out, n);
}

// Round 5
// 638.476 us; speedup vs baseline: 4.7988x; 1.0326x over previous
//
#include <hip/hip_runtime.h>

static constexpr float BN_EPS = 1e-5f;
typedef unsigned int uint;
typedef unsigned short ushort;

__device__ __forceinline__ void fatomic_add(float* p, float v) {
  unsafeAtomicAdd(p, v);  // HW global_atomic_add_f32
}

__device__ __forceinline__ ushort f2bf(float f) {  // f32 -> bf16 RNE
  uint u = __float_as_uint(f);
  u += 0x7fffu + ((u >> 16) & 1u);
  return (ushort)(u >> 16);
}

__device__ __forceinline__ float4 bf4_decode(uint2 r) {
  return make_float4(__uint_as_float(r.x << 16), __uint_as_float(r.x & 0xffff0000u),
                     __uint_as_float(r.y << 16), __uint_as_float(r.y & 0xffff0000u));
}

// edge count histogram keyed by col (single int atomic per edge)
__global__ void k_hist(const int* __restrict__ col, int* __restrict__ cnt, int e) {
  int i = blockIdx.x * 256 + threadIdx.x;
  if (i < e) atomicAdd(&cnt[col[i]], 1);
}

// ---- device-wide exclusive scan of cnt[n] (1024 elems/block) ----
__global__ __launch_bounds__(256) void k_scan_part(const int* __restrict__ cnt,
                                                   int* __restrict__ bsum, int n) {
  __shared__ int sm[256];
  int t = threadIdx.x;
  int base = blockIdx.x * 1024 + t * 4;
  int s = 0;
#pragma unroll
  for (int j = 0; j < 4; j++) {
    int i = base + j;
    if (i < n) s += cnt[i];
  }
  sm[t] = s;
  __syncthreads();
  for (int off = 128; off > 0; off >>= 1) {
    if (t < off) sm[t] += sm[t + off];
    __syncthreads();
  }
  if (t == 0) bsum[blockIdx.x] = sm[0];
}

__global__ __launch_bounds__(1024) void k_scan_mid(int* __restrict__ bsum, int nb) {
  __shared__ int sm[1024];
  int t = threadIdx.x;
  int v = (t < nb) ? bsum[t] : 0;
  sm[t] = v;
  __syncthreads();
  for (int off = 1; off < 1024; off <<= 1) {
    int o = (t >= off) ? sm[t - off] : 0;
    __syncthreads();
    sm[t] += o;
    __syncthreads();
  }
  if (t < nb) bsum[t] = sm[t] - v;  // exclusive block offsets
}

__global__ __launch_bounds__(256) void k_scan_apply(int* __restrict__ cnt,
                                                    int* __restrict__ ptr,
                                                    const int* __restrict__ bsum,
                                                    int n, int e) {
  __shared__ int sm[256];
  int t = threadIdx.x;
  int base = blockIdx.x * 1024 + t * 4;
  int v[4];
  int s = 0;
#pragma unroll
  for (int j = 0; j < 4; j++) {
    int i = base + j;
    v[j] = (i < n) ? cnt[i] : 0;
    s += v[j];
  }
  sm[t] = s;
  __syncthreads();
  for (int off = 1; off < 256; off <<= 1) {
    int o = (t >= off) ? sm[t - off] : 0;
    __syncthreads();
    sm[t] += o;
    __syncthreads();
  }
  int run = bsum[blockIdx.x] + sm[t] - s;
#pragma unroll
  for (int j = 0; j < 4; j++) {
    int i = base + j;
    if (i < n) {
      ptr[i] = run;
      cnt[i] = run;  // cursor init
      run += v[j];
    }
  }
  if (blockIdx.x == 0 && t == 0) ptr[n] = e;
}

// fill CSR entries with raw (row, ew) — no dis dependency
__global__ void k_fillcsr(const int* __restrict__ row, const int* __restrict__ col,
                          const float* __restrict__ ew, int* __restrict__ cursor,
                          int2* __restrict__ spair, int e) {
  int i = blockIdx.x * 256 + threadIdx.x;
  if (i >= e) return;
  int c = col[i];
  int p = atomicAdd(&cursor[c], 1);
  spair[p] = make_int2(row[i], __float_as_int(ew[i]));
}

// per-node: deg = 1 (self-loop) + segment-sum of ew; dis = rsqrt(deg). No atomics.
__global__ void k_degdis(const int* __restrict__ ptr, const int2* __restrict__ spair,
                         float* __restrict__ dis, int n) {
  int v = blockIdx.x * 256 + threadIdx.x;
  if (v >= n) return;
  int b = ptr[v], en = ptr[v + 1];
  float s = 1.0f;
  for (int j = b; j < en; j++) s += __int_as_float(spair[j].y);
  dis[v] = rsqrtf(s);
}

// fold dis[row] into stored edge weight (dis[col] applied in k_agg)
__global__ void k_scale(int2* __restrict__ spair, const float* __restrict__ dis, int e) {
  int i = blockIdx.x * 256 + threadIdx.x;
  if (i >= e) return;
  int2 m = spair[i];
  spair[i] = make_int2(m.x, __float_as_int(__int_as_float(m.y) * dis[m.x]));
}

// ---- aggregation + fused BN stats: one wave per node; 4 edge-groups x 16 lanes.
// acc = dis[v] * ( sum_e w_e*hw[row_e] + dis[v]*hw[v] ),  w_e = dis[row]*ew.
__global__ __launch_bounds__(256) void k_agg(
    const int* __restrict__ ptr, const int2* __restrict__ spair,
    const float* __restrict__ dis, const ushort* __restrict__ hwb,
    float* __restrict__ agg, float* __restrict__ stats, int n) {
  int lane = threadIdx.x & 63;
  int grp = lane >> 4;
  int li = lane & 15;
  int wid = blockIdx.x * 4 + (threadIdx.x >> 6);
  int nw = gridDim.x * 4;
  float st_s[4] = {0.f, 0.f, 0.f, 0.f};
  float st_q[4] = {0.f, 0.f, 0.f, 0.f};
  for (int v = wid; v < n; v += nw) {
    int beg = ptr[v], end = ptr[v + 1];
    float d = dis[v];
    float4 acc = make_float4(0.f, 0.f, 0.f, 0.f);
    if (grp == 0) {  // self-loop (one dis factor here, the other applied at the end)
      uint2 rs = *(const uint2*)(hwb + (size_t)v * 64 + li * 4);
      float4 f = bf4_decode(rs);
      acc = make_float4(d * f.x, d * f.y, d * f.z, d * f.w);
    }
    int j = beg + grp;
    if (j < end) {
      int2 m0 = spair[j];
      int2 m1 = (j + 4 < end) ? spair[j + 4] : m0;
      uint2 r0 = *(const uint2*)(hwb + (size_t)m0.x * 64 + li * 4);
      float w0 = __int_as_float(m0.y);
      while (j + 4 < end) {
        int2 m2 = (j + 8 < end) ? spair[j + 8] : m1;
        uint2 r1 = *(const uint2*)(hwb + (size_t)m1.x * 64 + li * 4);
        float w1 = __int_as_float(m1.y);
        float4 f = bf4_decode(r0);
        acc.x = fmaf(w0, f.x, acc.x);
        acc.y = fmaf(w0, f.y, acc.y);
        acc.z = fmaf(w0, f.z, acc.z);
        acc.w = fmaf(w0, f.w, acc.w);
        w0 = w1;
        r0 = r1;
        m1 = m2;
        j += 4;
      }
      float4 f = bf4_decode(r0);
      acc.x = fmaf(w0, f.x, acc.x);
      acc.y = fmaf(w0, f.y, acc.y);
      acc.z = fmaf(w0, f.z, acc.z);
      acc.w = fmaf(w0, f.w, acc.w);
    }
    // reduce across the 4 groups
    acc.x += __shfl_xor(acc.x, 16);
    acc.y += __shfl_xor(acc.y, 16);
    acc.z += __shfl_xor(acc.z, 16);
    acc.w += __shfl_xor(acc.w, 16);
    acc.x += __shfl_xor(acc.x, 32);
    acc.y += __shfl_xor(acc.y, 32);
    acc.z += __shfl_xor(acc.z, 32);
    acc.w += __shfl_xor(acc.w, 32);
    if (grp == 0) {
      acc.x *= d; acc.y *= d; acc.z *= d; acc.w *= d;
      *(float4*)(agg + (size_t)v * 64 + li * 4) = acc;
      st_s[0] += acc.x; st_s[1] += acc.y; st_s[2] += acc.z; st_s[3] += acc.w;
      st_q[0] = fmaf(acc.x, acc.x, st_q[0]);
      st_q[1] = fmaf(acc.y, acc.y, st_q[1]);
      st_q[2] = fmaf(acc.z, acc.z, st_q[2]);
      st_q[3] = fmaf(acc.w, acc.w, st_q[3]);
    }
  }
  // fused BN-stats block reduction
  __shared__ float rs[4][64];
  __shared__ float rq[4][64];
  int wv = threadIdx.x >> 6;
  if (grp == 0) {
#pragma unroll
    for (int j = 0; j < 4; j++) {
      rs[wv][li * 4 + j] = st_s[j];
      rq[wv][li * 4 + j] = st_q[j];
    }
  }
  __syncthreads();
  if (threadIdx.x < 64) {
    int c = threadIdx.x;
    float s = rs[0][c] + rs[1][c] + rs[2][c] + rs[3][c];
    float q = rq[0][c] + rq[1][c] + rq[2][c] + rq[3][c];
    fatomic_add(&stats[c], s);
    fatomic_add(&stats[64 + c], q);
  }
}

// Tiled fp32 GEMM: [n,K] @ [K,64] -> bf16 hw. Block = 256 = 64 rows x 4 col-segs.
// DUAL also writes x@Wb + bb as f32 (residual).
template <int K, bool DUAL>
__global__ __launch_bounds__(256) void k_gemm(
    const float* __restrict__ x, const float* __restrict__ Wa,
    ushort* __restrict__ outa, const float* __restrict__ Wb,
    const float* __restrict__ bb, float* __restrict__ outb, int n) {
  __shared__ float4 wA[K * 16];
  __shared__ float4 wB[DUAL ? K * 16 : 1];
  int tid = threadIdx.x;
  for (int i = tid; i < K * 16; i += 256) wA[i] = ((const float4*)Wa)[i];
  if (DUAL)
    for (int i = tid; i < K * 16; i += 256) wB[i] = ((const float4*)Wb)[i];
  __syncthreads();

  int r = tid >> 2, cseg = tid & 3;
  int rowi = blockIdx.x * 64 + r;
  if (rowi >= n) return;

  float acc1[16];
  float acc2[16];
#pragma unroll
  for (int j = 0; j < 16; j++) { acc1[j] = 0.f; acc2[j] = 0.f; }

  const float4* xr = (const float4*)(x + (size_t)rowi * K);
#pragma unroll 2
  for (int k4 = 0; k4 < K / 4; k4++) {
    float4 a = xr[k4];
#pragma unroll
    for (int u = 0; u < 4; u++) {
      float ak = (u == 0) ? a.x : (u == 1) ? a.y : (u == 2) ? a.z : a.w;
      int k = k4 * 4 + u;
      const float4* wr = &wA[k * 16 + cseg * 4];
#pragma unroll
      for (int q = 0; q < 4; q++) {
        float4 w = wr[q];
        acc1[q * 4 + 0] = fmaf(ak, w.x, acc1[q * 4 + 0]);
        acc1[q * 4 + 1] = fmaf(ak, w.y, acc1[q * 4 + 1]);
        acc1[q * 4 + 2] = fmaf(ak, w.z, acc1[q * 4 + 2]);
        acc1[q * 4 + 3] = fmaf(ak, w.w, acc1[q * 4 + 3]);
      }
      if (DUAL) {
        const float4* wr2 = &wB[k * 16 + cseg * 4];
#pragma unroll
        for (int q = 0; q < 4; q++) {
          float4 w = wr2[q];
          acc2[q * 4 + 0] = fmaf(ak, w.x, acc2[q * 4 + 0]);
          acc2[q * 4 + 1] = fmaf(ak, w.y, acc2[q * 4 + 1]);
          acc2[q * 4 + 2] = fmaf(ak, w.z, acc2[q * 4 + 2]);
          acc2[q * 4 + 3] = fmaf(ak, w.w, acc2[q * 4 + 3]);
        }
      }
    }
  }

  ushort* o1 = outa + (size_t)rowi * 64 + cseg * 16;
  uint pk[8];
#pragma unroll
  for (int q = 0; q < 8; q++)
    pk[q] = (uint)f2bf(acc1[2 * q]) | ((uint)f2bf(acc1[2 * q + 1]) << 16);
  ((uint4*)o1)[0] = make_uint4(pk[0], pk[1], pk[2], pk[3]);
  ((uint4*)o1)[1] = make_uint4(pk[4], pk[5], pk[6], pk[7]);

  if (DUAL) {
    float* o2 = outb + (size_t)rowi * 64 + cseg * 16;
#pragma unroll
    for (int q = 0; q < 4; q++) {
      float4 bv = ((const float4*)bb)[cseg * 4 + q];
      ((float4*)o2)[q] = make_float4(acc2[q * 4 + 0] + bv.x, acc2[q * 4 + 1] + bv.y,
                                     acc2[q * 4 + 2] + bv.z, acc2[q * 4 + 3] + bv.w);
    }
  }
}

// out = relu(g*(agg-mu)*rsqrt(var+eps)+beta) + res   (conv bias cancels in BN)
__global__ __launch_bounds__(256) void k_bnrelu(
    const float* __restrict__ agg, const float* __restrict__ res,
    const float* __restrict__ stats, const float* __restrict__ g,
    const float* __restrict__ beta, float* __restrict__ out, int n) {
  int idx = blockIdx.x * 256 + threadIdx.x;
  if (idx >= n * 16) return;
  int c4 = (idx & 15) * 4;
  float invN = 1.0f / (float)n;
  float4 a = ((const float4*)agg)[idx];
  float4 rr = ((const float4*)res)[idx];
  float av[4] = {a.x, a.y, a.z, a.w};
  float rv[4] = {rr.x, rr.y, rr.z, rr.w};
  float vo[4];
#pragma unroll
  for (int j = 0; j < 4; j++) {
    int c = c4 + j;
    float mu = stats[c] * invN;
    float var = stats[64 + c] * invN - mu * mu;
    float sc = g[c] * rsqrtf(var + BN_EPS);
    float v = (av[j] - mu) * sc + beta[c];
    vo[j] = fmaxf(v, 0.0f) + rv[j];
  }
  ((float4*)out)[idx] = make_float4(vo[0], vo[1], vo[2], vo[3]);
}

extern "C" void kernel_launch(void* const* d_in, const int* in_sizes, int n_in,
                              void* d_out, int out_size, void* d_ws, size_t ws_size,
                              hipStream_t stream) {
  const float* x = (const float*)d_in[0];
  const int* ei = (const int*)d_in[1];
  const float* ew = (const float*)d_in[2];
  const float* W1 = (const float*)d_in[3];
  const float* g1 = (const float*)d_in[5];
  const float* be1 = (const float*)d_in[6];
  const float* W2 = (const float*)d_in[7];
  const float* g2 = (const float*)d_in[9];
  const float* be2 = (const float*)d_in[10];
  const float* pW = (const float*)d_in[11];
  const float* pb = (const float*)d_in[12];

  int n = in_sizes[0] / 128;
  int e = in_sizes[1] / 2;
  const int* row = ei;      // source
  const int* col = ei + e;  // target

  // workspace layout
  float* ws = (float*)d_ws;
  float* dis = ws;                             // n
  int* ptr = (int*)(dis + n);                  // n+4
  int* cursor = ptr + n + 4;                   // n
  int* bsum = cursor + n;                      // 1024
  int2* spair = (int2*)(bsum + 1024);          // e int2
  ushort* hwb = (ushort*)(spair + e);          // n*64 bf16 (hw1, then hw2)
  float* bufR = (float*)(hwb + (size_t)n * 64);  // n*64 (residual)
  float* bufB = bufR + (size_t)n * 64;         // n*64 (agg)
  float* bufA = bufB + (size_t)n * 64;         // n*64 (h)
  float* stats = bufA + (size_t)n * 64;        // 128

  float* out = (float*)d_out;

  int nb_n = (n + 255) / 256;
  int nb_e = (e + 255) / 256;
  int nb_g = (n + 63) / 64;
  int nb_b = (n * 16 + 255) / 256;
  int nb_sc = (n + 1023) / 1024;

  // CSR build + gcn_norm
  hipMemsetAsync(cursor, 0, n * sizeof(int), stream);
  k_hist<<<nb_e, 256, 0, stream>>>(col, cursor, e);
  k_scan_part<<<nb_sc, 256, 0, stream>>>(cursor, bsum, n);
  k_scan_mid<<<1, 1024, 0, stream>>>(bsum, nb_sc);
  k_scan_apply<<<nb_sc, 256, 0, stream>>>(cursor, ptr, bsum, n, e);
  k_fillcsr<<<nb_e, 256, 0, stream>>>(row, col, ew, cursor, spair, e);
  k_degdis<<<nb_n, 256, 0, stream>>>(ptr, spair, dis, n);
  k_scale<<<nb_e, 256, 0, stream>>>(spair, dis, e);

  // layer 1
  k_gemm<128, true><<<nb_g, 256, 0, stream>>>(x, W1, hwb, pW, pb, bufR, n);
  hipMemsetAsync(stats, 0, 128 * sizeof(float), stream);
  k_agg<<<2048, 256, 0, stream>>>(ptr, spair, dis, hwb, bufB, stats, n);
  k_bnrelu<<<nb_b, 256, 0, stream>>>(bufB, bufR, stats, g1, be1, bufA, n);

  // layer 2
  k_gemm<64, false><<<nb_g, 256, 0, stream>>>(bufA, W2, hwb, nullptr, nullptr, nullptr, n);
  hipMemsetAsync(stats, 0, 128 * sizeof(float), stream);
  k_agg<<<2048, 256, 0, stream>>>(ptr, spair, dis, hwb, bufB, stats, n);
  k_bnrelu<<<nb_b, 256, 0, stream>>>(bufB, bufA, stats, g2, be2, out, n);
}

// Round 6
// 621.606 us; speedup vs baseline: 4.9290x; 1.0271x over previous
//
#include <hip/hip_runtime.h>

static constexpr float BN_EPS = 1e-5f;
typedef unsigned int uint;
typedef unsigned short ushort;

__device__ __forceinline__ void fatomic_add(float* p, float v) {
  unsafeAtomicAdd(p, v);  // HW global_atomic_add_f32
}

__device__ __forceinline__ ushort f2bf(float f) {  // f32 -> bf16 RNE
  uint u = __float_as_uint(f);
  u += 0x7fffu + ((u >> 16) & 1u);
  return (ushort)(u >> 16);
}

__device__ __forceinline__ float4 bf4_decode(uint2 r) {
  return make_float4(__uint_as_float(r.x << 16), __uint_as_float(r.x & 0xffff0000u),
                     __uint_as_float(r.y << 16), __uint_as_float(r.y & 0xffff0000u));
}

// edge count histogram keyed by col (single int atomic per edge)
__global__ void k_hist(const int* __restrict__ col, int* __restrict__ cnt, int e) {
  int i = blockIdx.x * 256 + threadIdx.x;
  if (i < e) atomicAdd(&cnt[col[i]], 1);
}

// ---- device-wide exclusive scan of cnt[n] (1024 elems/block) ----
__global__ __launch_bounds__(256) void k_scan_part(const int* __restrict__ cnt,
                                                   int* __restrict__ bsum, int n) {
  __shared__ int sm[256];
  int t = threadIdx.x;
  int base = blockIdx.x * 1024 + t * 4;
  int s = 0;
#pragma unroll
  for (int j = 0; j < 4; j++) {
    int i = base + j;
    if (i < n) s += cnt[i];
  }
  sm[t] = s;
  __syncthreads();
  for (int off = 128; off > 0; off >>= 1) {
    if (t < off) sm[t] += sm[t + off];
    __syncthreads();
  }
  if (t == 0) bsum[blockIdx.x] = sm[0];
}

__global__ __launch_bounds__(1024) void k_scan_mid(int* __restrict__ bsum, int nb) {
  __shared__ int sm[1024];
  int t = threadIdx.x;
  int v = (t < nb) ? bsum[t] : 0;
  sm[t] = v;
  __syncthreads();
  for (int off = 1; off < 1024; off <<= 1) {
    int o = (t >= off) ? sm[t - off] : 0;
    __syncthreads();
    sm[t] += o;
    __syncthreads();
  }
  if (t < nb) bsum[t] = sm[t] - v;  // exclusive block offsets
}

__global__ __launch_bounds__(256) void k_scan_apply(int* __restrict__ cnt,
                                                    int* __restrict__ ptr,
                                                    const int* __restrict__ bsum,
                                                    int n, int e) {
  __shared__ int sm[256];
  int t = threadIdx.x;
  int base = blockIdx.x * 1024 + t * 4;
  int v[4];
  int s = 0;
#pragma unroll
  for (int j = 0; j < 4; j++) {
    int i = base + j;
    v[j] = (i < n) ? cnt[i] : 0;
    s += v[j];
  }
  sm[t] = s;
  __syncthreads();
  for (int off = 1; off < 256; off <<= 1) {
    int o = (t >= off) ? sm[t - off] : 0;
    __syncthreads();
    sm[t] += o;
    __syncthreads();
  }
  int run = bsum[blockIdx.x] + sm[t] - s;
#pragma unroll
  for (int j = 0; j < 4; j++) {
    int i = base + j;
    if (i < n) {
      ptr[i] = run;
      cnt[i] = run;  // cursor init
      run += v[j];
    }
  }
  if (blockIdx.x == 0 && t == 0) ptr[n] = e;
}

// fill CSR entries with raw (row, ew)
__global__ void k_fillcsr(const int* __restrict__ row, const int* __restrict__ col,
                          const float* __restrict__ ew, int* __restrict__ cursor,
                          int2* __restrict__ spair, int e) {
  int i = blockIdx.x * 256 + threadIdx.x;
  if (i >= e) return;
  int c = col[i];
  int p = atomicAdd(&cursor[c], 1);
  spair[p] = make_int2(row[i], __float_as_int(ew[i]));
}

// per-node: deg = 1 (self-loop) + segment-sum of ew; dis = rsqrt(deg). No atomics.
__global__ void k_degdis(const int* __restrict__ ptr, const int2* __restrict__ spair,
                         float* __restrict__ dis, int n) {
  int v = blockIdx.x * 256 + threadIdx.x;
  if (v >= n) return;
  int b = ptr[v], en = ptr[v + 1];
  float s = 1.0f;
  for (int j = b; j < en; j++) s += __int_as_float(spair[j].y);
  dis[v] = rsqrtf(s);
}

// fold dis[row] into stored edge weight (dis[col] applied in k_agg)
__global__ void k_scale(int2* __restrict__ spair, const float* __restrict__ dis, int e) {
  int i = blockIdx.x * 256 + threadIdx.x;
  if (i >= e) return;
  int2 m = spair[i];
  spair[i] = make_int2(m.x, __float_as_int(__int_as_float(m.y) * dis[m.x]));
}

// ---- aggregation + fused BN stats: one wave per node; 4 edge-groups x 16 lanes.
__global__ __launch_bounds__(256) void k_agg(
    const int* __restrict__ ptr, const int2* __restrict__ spair,
    const float* __restrict__ dis, const ushort* __restrict__ hwb,
    float* __restrict__ agg, float* __restrict__ stats, int n) {
  int lane = threadIdx.x & 63;
  int grp = lane >> 4;
  int li = lane & 15;
  int wid = blockIdx.x * 4 + (threadIdx.x >> 6);
  int nw = gridDim.x * 4;
  float st_s[4] = {0.f, 0.f, 0.f, 0.f};
  float st_q[4] = {0.f, 0.f, 0.f, 0.f};
  for (int v = wid; v < n; v += nw) {
    int beg = ptr[v], end = ptr[v + 1];
    float d = dis[v];
    float4 acc = make_float4(0.f, 0.f, 0.f, 0.f);
    if (grp == 0) {  // self-loop
      uint2 rs = *(const uint2*)(hwb + (size_t)v * 64 + li * 4);
      float4 f = bf4_decode(rs);
      acc = make_float4(d * f.x, d * f.y, d * f.z, d * f.w);
    }
    int j = beg + grp;
    if (j < end) {
      int2 m0 = spair[j];
      int2 m1 = (j + 4 < end) ? spair[j + 4] : m0;
      uint2 r0 = *(const uint2*)(hwb + (size_t)m0.x * 64 + li * 4);
      float w0 = __int_as_float(m0.y);
      while (j + 4 < end) {
        int2 m2 = (j + 8 < end) ? spair[j + 8] : m1;
        uint2 r1 = *(const uint2*)(hwb + (size_t)m1.x * 64 + li * 4);
        float w1 = __int_as_float(m1.y);
        float4 f = bf4_decode(r0);
        acc.x = fmaf(w0, f.x, acc.x);
        acc.y = fmaf(w0, f.y, acc.y);
        acc.z = fmaf(w0, f.z, acc.z);
        acc.w = fmaf(w0, f.w, acc.w);
        w0 = w1;
        r0 = r1;
        m1 = m2;
        j += 4;
      }
      float4 f = bf4_decode(r0);
      acc.x = fmaf(w0, f.x, acc.x);
      acc.y = fmaf(w0, f.y, acc.y);
      acc.z = fmaf(w0, f.z, acc.z);
      acc.w = fmaf(w0, f.w, acc.w);
    }
    acc.x += __shfl_xor(acc.x, 16);
    acc.y += __shfl_xor(acc.y, 16);
    acc.z += __shfl_xor(acc.z, 16);
    acc.w += __shfl_xor(acc.w, 16);
    acc.x += __shfl_xor(acc.x, 32);
    acc.y += __shfl_xor(acc.y, 32);
    acc.z += __shfl_xor(acc.z, 32);
    acc.w += __shfl_xor(acc.w, 32);
    if (grp == 0) {
      acc.x *= d; acc.y *= d; acc.z *= d; acc.w *= d;
      *(float4*)(agg + (size_t)v * 64 + li * 4) = acc;
      st_s[0] += acc.x; st_s[1] += acc.y; st_s[2] += acc.z; st_s[3] += acc.w;
      st_q[0] = fmaf(acc.x, acc.x, st_q[0]);
      st_q[1] = fmaf(acc.y, acc.y, st_q[1]);
      st_q[2] = fmaf(acc.z, acc.z, st_q[2]);
      st_q[3] = fmaf(acc.w, acc.w, st_q[3]);
    }
  }
  __shared__ float rs[4][64];
  __shared__ float rq[4][64];
  int wv = threadIdx.x >> 6;
  if (grp == 0) {
#pragma unroll
    for (int j = 0; j < 4; j++) {
      rs[wv][li * 4 + j] = st_s[j];
      rq[wv][li * 4 + j] = st_q[j];
    }
  }
  __syncthreads();
  if (threadIdx.x < 64) {
    int c = threadIdx.x;
    float s = rs[0][c] + rs[1][c] + rs[2][c] + rs[3][c];
    float q = rq[0][c] + rq[1][c] + rq[2][c] + rq[3][c];
    fatomic_add(&stats[c], s);
    fatomic_add(&stats[64 + c], q);
  }
}

// ---- GEMM v2: [n,K] @ [K,N] with 4 rows x 16 cols per thread.
// N=128 SPLIT: cols 0-63 = Wa -> bf16 out; cols 64-127 = Wb (+bias bb) -> f32 out.
// N=64: Wa -> bf16 out. W staged in LDS in K-tiles of KT (f32).
// LDS reads amortized: 4 ds_read_b128 per k serve 64 FMAs (was 8 per 32).
template <int K, int N, int KT, bool SPLIT>
__global__ __launch_bounds__(256) void k_gemmv(
    const float* __restrict__ x, const float* __restrict__ Wa,
    const float* __restrict__ Wb, const float* __restrict__ bb,
    ushort* __restrict__ ob, float* __restrict__ of, int n) {
  constexpr int CS = N / 16;   // col segments
  constexpr int RS = 256 / CS; // row slots
  constexpr int TR = RS * 4;   // tile rows per block
  __shared__ float wS[KT * N];
  int tid = threadIdx.x;
  int cseg = tid % CS;
  int rslot = tid / CS;
  int baseRow = blockIdx.x * TR;

  float acc[4][16];
#pragma unroll
  for (int i = 0; i < 4; i++)
#pragma unroll
    for (int j = 0; j < 16; j++) acc[i][j] = 0.f;

  int rows[4];
  bool ok[4];
#pragma unroll
  for (int i = 0; i < 4; i++) {
    rows[i] = baseRow + rslot + i * RS;
    ok[i] = rows[i] < n;
  }

  for (int kt = 0; kt < K; kt += KT) {
    __syncthreads();
    for (int idx = tid; idx < KT * N / 4; idx += 256) {
      int kk = idx / (N / 4);
      int c4 = idx % (N / 4);
      const float* src = (SPLIT && c4 >= 16) ? Wb : Wa;
      int cc = SPLIT ? (c4 & 15) : c4;
      ((float4*)wS)[idx] = ((const float4*)(src + (size_t)(kt + kk) * 64))[cc];
    }
    __syncthreads();
#pragma unroll 2
    for (int k4 = 0; k4 < KT / 4; k4++) {
      float4 xv[4];
#pragma unroll
      for (int i = 0; i < 4; i++)
        xv[i] = ok[i] ? *(const float4*)(x + (size_t)rows[i] * K + kt + k4 * 4)
                      : make_float4(0.f, 0.f, 0.f, 0.f);
#pragma unroll
      for (int u = 0; u < 4; u++) {
        const float4* wr = (const float4*)(wS + (k4 * 4 + u) * N + cseg * 16);
        float4 w0 = wr[0], w1 = wr[1], w2 = wr[2], w3 = wr[3];
#pragma unroll
        for (int i = 0; i < 4; i++) {
          float ak = (u == 0) ? xv[i].x : (u == 1) ? xv[i].y : (u == 2) ? xv[i].z : xv[i].w;
          acc[i][0] = fmaf(ak, w0.x, acc[i][0]);
          acc[i][1] = fmaf(ak, w0.y, acc[i][1]);
          acc[i][2] = fmaf(ak, w0.z, acc[i][2]);
          acc[i][3] = fmaf(ak, w0.w, acc[i][3]);
          acc[i][4] = fmaf(ak, w1.x, acc[i][4]);
          acc[i][5] = fmaf(ak, w1.y, acc[i][5]);
          acc[i][6] = fmaf(ak, w1.z, acc[i][6]);
          acc[i][7] = fmaf(ak, w1.w, acc[i][7]);
          acc[i][8] = fmaf(ak, w2.x, acc[i][8]);
          acc[i][9] = fmaf(ak, w2.y, acc[i][9]);
          acc[i][10] = fmaf(ak, w2.z, acc[i][10]);
          acc[i][11] = fmaf(ak, w2.w, acc[i][11]);
          acc[i][12] = fmaf(ak, w3.x, acc[i][12]);
          acc[i][13] = fmaf(ak, w3.y, acc[i][13]);
          acc[i][14] = fmaf(ak, w3.z, acc[i][14]);
          acc[i][15] = fmaf(ak, w3.w, acc[i][15]);
        }
      }
    }
  }

  if (!SPLIT || cseg < CS / 2) {  // bf16 output half (or all, for N=64)
    int co = SPLIT ? cseg * 16 : cseg * 16;
#pragma unroll
    for (int i = 0; i < 4; i++) {
      if (!ok[i]) continue;
      ushort* o = ob + (size_t)rows[i] * 64 + co;
      uint pk[8];
#pragma unroll
      for (int q = 0; q < 8; q++)
        pk[q] = (uint)f2bf(acc[i][2 * q]) | ((uint)f2bf(acc[i][2 * q + 1]) << 16);
      ((uint4*)o)[0] = make_uint4(pk[0], pk[1], pk[2], pk[3]);
      ((uint4*)o)[1] = make_uint4(pk[4], pk[5], pk[6], pk[7]);
    }
  } else {  // f32 residual half with bias
    int cs = cseg - CS / 2;
    float4 bv[4];
#pragma unroll
    for (int q = 0; q < 4; q++) bv[q] = ((const float4*)bb)[cs * 4 + q];
#pragma unroll
    for (int i = 0; i < 4; i++) {
      if (!ok[i]) continue;
      float* o = of + (size_t)rows[i] * 64 + cs * 16;
#pragma unroll
      for (int q = 0; q < 4; q++)
        ((float4*)o)[q] = make_float4(acc[i][q * 4 + 0] + bv[q].x, acc[i][q * 4 + 1] + bv[q].y,
                                      acc[i][q * 4 + 2] + bv[q].z, acc[i][q * 4 + 3] + bv[q].w);
    }
  }
}

// out = relu(g*(agg-mu)*rsqrt(var+eps)+beta) + res   (conv bias cancels in BN)
__global__ __launch_bounds__(256) void k_bnrelu(
    const float* __restrict__ agg, const float* __restrict__ res,
    const float* __restrict__ stats, const float* __restrict__ g,
    const float* __restrict__ beta, float* __restrict__ out, int n) {
  int idx = blockIdx.x * 256 + threadIdx.x;
  if (idx >= n * 16) return;
  int c4 = (idx & 15) * 4;
  float invN = 1.0f / (float)n;
  float4 a = ((const float4*)agg)[idx];
  float4 rr = ((const float4*)res)[idx];
  float av[4] = {a.x, a.y, a.z, a.w};
  float rv[4] = {rr.x, rr.y, rr.z, rr.w};
  float vo[4];
#pragma unroll
  for (int j = 0; j < 4; j++) {
    int c = c4 + j;
    float mu = stats[c] * invN;
    float var = stats[64 + c] * invN - mu * mu;
    float sc = g[c] * rsqrtf(var + BN_EPS);
    float v = (av[j] - mu) * sc + beta[c];
    vo[j] = fmaxf(v, 0.0f) + rv[j];
  }
  ((float4*)out)[idx] = make_float4(vo[0], vo[1], vo[2], vo[3]);
}

extern "C" void kernel_launch(void* const* d_in, const int* in_sizes, int n_in,
                              void* d_out, int out_size, void* d_ws, size_t ws_size,
                              hipStream_t stream) {
  const float* x = (const float*)d_in[0];
  const int* ei = (const int*)d_in[1];
  const float* ew = (const float*)d_in[2];
  const float* W1 = (const float*)d_in[3];
  const float* g1 = (const float*)d_in[5];
  const float* be1 = (const float*)d_in[6];
  const float* W2 = (const float*)d_in[7];
  const float* g2 = (const float*)d_in[9];
  const float* be2 = (const float*)d_in[10];
  const float* pW = (const float*)d_in[11];
  const float* pb = (const float*)d_in[12];

  int n = in_sizes[0] / 128;
  int e = in_sizes[1] / 2;
  const int* row = ei;      // source
  const int* col = ei + e;  // target

  // workspace layout
  float* ws = (float*)d_ws;
  float* dis = ws;                             // n
  int* ptr = (int*)(dis + n);                  // n+4
  int* cursor = ptr + n + 4;                   // n
  int* bsum = cursor + n;                      // 1024
  int2* spair = (int2*)(bsum + 1024);          // e int2
  ushort* hwb = (ushort*)(spair + e);          // n*64 bf16 (hw1, then hw2)
  float* bufR = (float*)(hwb + (size_t)n * 64);  // n*64 (residual)
  float* bufB = bufR + (size_t)n * 64;         // n*64 (agg)
  float* bufA = bufB + (size_t)n * 64;         // n*64 (h)
  float* stats = bufA + (size_t)n * 64;        // 128

  float* out = (float*)d_out;

  int nb_n = (n + 255) / 256;
  int nb_e = (e + 255) / 256;
  int nb_b = (n * 16 + 255) / 256;
  int nb_sc = (n + 1023) / 1024;
  int nb_g1 = (n + 127) / 128;  // TR=128 for N=128 kernel
  int nb_g2 = (n + 255) / 256;  // TR=256 for N=64 kernel

  // CSR build + gcn_norm
  hipMemsetAsync(cursor, 0, n * sizeof(int), stream);
  k_hist<<<nb_e, 256, 0, stream>>>(col, cursor, e);
  k_scan_part<<<nb_sc, 256, 0, stream>>>(cursor, bsum, n);
  k_scan_mid<<<1, 1024, 0, stream>>>(bsum, nb_sc);
  k_scan_apply<<<nb_sc, 256, 0, stream>>>(cursor, ptr, bsum, n, e);
  k_fillcsr<<<nb_e, 256, 0, stream>>>(row, col, ew, cursor, spair, e);
  k_degdis<<<nb_n, 256, 0, stream>>>(ptr, spair, dis, n);
  k_scale<<<nb_e, 256, 0, stream>>>(spair, dis, e);

  // layer 1: combined [x@W1 -> bf16 hwb | x@pW + pb -> f32 bufR]
  k_gemmv<128, 128, 64, true><<<nb_g1, 256, 0, stream>>>(x, W1, pW, pb, hwb, bufR, n);
  hipMemsetAsync(stats, 0, 128 * sizeof(float), stream);
  k_agg<<<2048, 256, 0, stream>>>(ptr, spair, dis, hwb, bufB, stats, n);
  k_bnrelu<<<nb_b, 256, 0, stream>>>(bufB, bufR, stats, g1, be1, bufA, n);

  // layer 2
  k_gemmv<64, 64, 64, false><<<nb_g2, 256, 0, stream>>>(bufA, W2, nullptr, nullptr, hwb, nullptr, n);
  hipMemsetAsync(stats, 0, 128 * sizeof(float), stream);
  k_agg<<<2048, 256, 0, stream>>>(ptr, spair, dis, hwb, bufB, stats, n);
  k_bnrelu<<<nb_b, 256, 0, stream>>>(bufB, bufA, stats, g2, be2, out, n);
}

// Round 7
// 539.702 us; speedup vs baseline: 5.6770x; 1.1518x over previous
//
#include <hip/hip_runtime.h>

static constexpr float BN_EPS = 1e-5f;
typedef unsigned int uint;
typedef unsigned short ushort;

__device__ __forceinline__ void fatomic_add(float* p, float v) {
  unsafeAtomicAdd(p, v);  // HW global_atomic_add_f32
}

__device__ __forceinline__ ushort f2bf(float f) {  // f32 -> bf16 RNE
  uint u = __float_as_uint(f);
  u += 0x7fffu + ((u >> 16) & 1u);
  return (ushort)(u >> 16);
}

__device__ __forceinline__ float4 bf4_decode(uint2 r) {
  return make_float4(__uint_as_float(r.x << 16), __uint_as_float(r.x & 0xffff0000u),
                     __uint_as_float(r.y << 16), __uint_as_float(r.y & 0xffff0000u));
}

// histogram keyed by col; stores each edge's arrival rank (for atomic-free fill)
__global__ void k_hist(const int* __restrict__ col, int* __restrict__ cnt,
                       int* __restrict__ rank, int e) {
  int i = blockIdx.x * 256 + threadIdx.x;
  if (i < e) rank[i] = atomicAdd(&cnt[col[i]], 1);
}

// ---- device-wide exclusive scan of cnt[n] (1024 elems/block) ----
__global__ __launch_bounds__(256) void k_scan_part(const int* __restrict__ cnt,
                                                   int* __restrict__ bsum, int n) {
  __shared__ int sm[256];
  int t = threadIdx.x;
  int base = blockIdx.x * 1024 + t * 4;
  int s = 0;
#pragma unroll
  for (int j = 0; j < 4; j++) {
    int i = base + j;
    if (i < n) s += cnt[i];
  }
  sm[t] = s;
  __syncthreads();
  for (int off = 128; off > 0; off >>= 1) {
    if (t < off) sm[t] += sm[t + off];
    __syncthreads();
  }
  if (t == 0) bsum[blockIdx.x] = sm[0];
}

__global__ __launch_bounds__(1024) void k_scan_mid(int* __restrict__ bsum, int nb) {
  __shared__ int sm[1024];
  int t = threadIdx.x;
  int v = (t < nb) ? bsum[t] : 0;
  sm[t] = v;
  __syncthreads();
  for (int off = 1; off < 1024; off <<= 1) {
    int o = (t >= off) ? sm[t - off] : 0;
    __syncthreads();
    sm[t] += o;
    __syncthreads();
  }
  if (t < nb) bsum[t] = sm[t] - v;  // exclusive block offsets
}

__global__ __launch_bounds__(256) void k_scan_apply(const int* __restrict__ cnt,
                                                    int* __restrict__ ptr,
                                                    const int* __restrict__ bsum,
                                                    int n, int e) {
  __shared__ int sm[256];
  int t = threadIdx.x;
  int base = blockIdx.x * 1024 + t * 4;
  int v[4];
  int s = 0;
#pragma unroll
  for (int j = 0; j < 4; j++) {
    int i = base + j;
    v[j] = (i < n) ? cnt[i] : 0;
    s += v[j];
  }
  sm[t] = s;
  __syncthreads();
  for (int off = 1; off < 256; off <<= 1) {
    int o = (t >= off) ? sm[t - off] : 0;
    __syncthreads();
    sm[t] += o;
    __syncthreads();
  }
  int run = bsum[blockIdx.x] + sm[t] - s;
#pragma unroll
  for (int j = 0; j < 4; j++) {
    int i = base + j;
    if (i < n) {
      ptr[i] = run;
      run += v[j];
    }
  }
  if (blockIdx.x == 0 && t == 0) ptr[n] = e;
}

// atomic-free CSR fill: slot = ptr[col] + rank
__global__ void k_fillcsr(const int* __restrict__ row, const int* __restrict__ col,
                          const float* __restrict__ ew, const int* __restrict__ ptr,
                          const int* __restrict__ rank, int2* __restrict__ spair, int e) {
  int i = blockIdx.x * 256 + threadIdx.x;
  if (i >= e) return;
  int p = ptr[col[i]] + rank[i];
  spair[p] = make_int2(row[i], __float_as_int(ew[i]));
}

// per-node: deg = 1 (self-loop) + segment-sum of ew; dis = rsqrt(deg). No atomics.
__global__ void k_degdis(const int* __restrict__ ptr, const int2* __restrict__ spair,
                         float* __restrict__ dis, int n) {
  int v = blockIdx.x * 256 + threadIdx.x;
  if (v >= n) return;
  int b = ptr[v], en = ptr[v + 1];
  float s = 1.0f;
  for (int j = b; j < en; j++) s += __int_as_float(spair[j].y);
  dis[v] = rsqrtf(s);
}

// fold dis[row] into stored edge weight (dis[col] applied in k_agg)
__global__ void k_scale(int2* __restrict__ spair, const float* __restrict__ dis, int e) {
  int i = blockIdx.x * 256 + threadIdx.x;
  if (i >= e) return;
  int2 m = spair[i];
  spair[i] = make_int2(m.x, __float_as_int(__int_as_float(m.y) * dis[m.x]));
}

// ---- aggregation + fused BN stats.
// One NODE per 16-lane group (4 nodes/wave): the group walks its node's full
// edge list with a depth-3 software pipeline (run length ~deg=16, no per-node
// cross-group shuffles). BN-stats reduced once at kernel end.
__global__ __launch_bounds__(256) void k_agg(
    const int* __restrict__ ptr, const int2* __restrict__ spair,
    const float* __restrict__ dis, const ushort* __restrict__ hwb,
    float* __restrict__ agg, float* __restrict__ stats, int n) {
  int lane = threadIdx.x & 63;
  int grp = lane >> 4;
  int li = lane & 15;
  int wid = blockIdx.x * 4 + (threadIdx.x >> 6);
  int nw = gridDim.x * 4;
  float st_s[4] = {0.f, 0.f, 0.f, 0.f};
  float st_q[4] = {0.f, 0.f, 0.f, 0.f};

  for (int vb = wid * 4; vb < n; vb += nw * 4) {
    int v = vb + grp;
    bool on = v < n;
    int beg = 0, end = 0;
    float d = 0.f;
    float4 acc = make_float4(0.f, 0.f, 0.f, 0.f);
    if (on) {
      beg = ptr[v];
      end = ptr[v + 1];
      d = dis[v];
      uint2 rs = *(const uint2*)(hwb + (size_t)v * 64 + li * 4);
      float4 f = bf4_decode(rs);
      acc = make_float4(d * f.x, d * f.y, d * f.z, d * f.w);  // self-loop (1 of 2 dis)
    }
    int j = beg;
    int2 m0, m1, m2;
    uint2 r0, r1;
    if (j < end) m0 = spair[j];
    if (j + 1 < end) m1 = spair[j + 1];
    if (j + 2 < end) m2 = spair[j + 2];
    if (j < end) r0 = *(const uint2*)(hwb + (size_t)m0.x * 64 + li * 4);
    if (j + 1 < end) r1 = *(const uint2*)(hwb + (size_t)m1.x * 64 + li * 4);
    while (j + 2 < end) {
      int2 m3 = (j + 3 < end) ? spair[j + 3] : m2;
      uint2 r2 = *(const uint2*)(hwb + (size_t)m2.x * 64 + li * 4);
      float w0 = __int_as_float(m0.y);
      float4 f = bf4_decode(r0);
      acc.x = fmaf(w0, f.x, acc.x);
      acc.y = fmaf(w0, f.y, acc.y);
      acc.z = fmaf(w0, f.z, acc.z);
      acc.w = fmaf(w0, f.w, acc.w);
      m0 = m1; m1 = m2; m2 = m3;
      r0 = r1; r1 = r2;
      j++;
    }
    if (j < end) {
      float w0 = __int_as_float(m0.y);
      float4 f = bf4_decode(r0);
      acc.x = fmaf(w0, f.x, acc.x);
      acc.y = fmaf(w0, f.y, acc.y);
      acc.z = fmaf(w0, f.z, acc.z);
      acc.w = fmaf(w0, f.w, acc.w);
      j++;
      m0 = m1;
      r0 = r1;
    }
    if (j < end) {
      float w0 = __int_as_float(m0.y);
      float4 f = bf4_decode(r0);
      acc.x = fmaf(w0, f.x, acc.x);
      acc.y = fmaf(w0, f.y, acc.y);
      acc.z = fmaf(w0, f.z, acc.z);
      acc.w = fmaf(w0, f.w, acc.w);
    }
    if (on) {
      acc.x *= d; acc.y *= d; acc.z *= d; acc.w *= d;  // 2nd dis factor
      *(float4*)(agg + (size_t)v * 64 + li * 4) = acc;
      st_s[0] += acc.x; st_s[1] += acc.y; st_s[2] += acc.z; st_s[3] += acc.w;
      st_q[0] = fmaf(acc.x, acc.x, st_q[0]);
      st_q[1] = fmaf(acc.y, acc.y, st_q[1]);
      st_q[2] = fmaf(acc.z, acc.z, st_q[2]);
      st_q[3] = fmaf(acc.w, acc.w, st_q[3]);
    }
  }

  // cross-group reduce (channels of lane l == channels of lane l^16, l^32)
#pragma unroll
  for (int j = 0; j < 4; j++) {
    st_s[j] += __shfl_xor(st_s[j], 16);
    st_s[j] += __shfl_xor(st_s[j], 32);
    st_q[j] += __shfl_xor(st_q[j], 16);
    st_q[j] += __shfl_xor(st_q[j], 32);
  }
  __shared__ float rs[4][64];
  __shared__ float rq[4][64];
  int wv = threadIdx.x >> 6;
  if (grp == 0) {
#pragma unroll
    for (int j = 0; j < 4; j++) {
      rs[wv][li * 4 + j] = st_s[j];
      rq[wv][li * 4 + j] = st_q[j];
    }
  }
  __syncthreads();
  if (threadIdx.x < 64) {
    int c = threadIdx.x;
    float s = rs[0][c] + rs[1][c] + rs[2][c] + rs[3][c];
    float q = rq[0][c] + rq[1][c] + rq[2][c] + rq[3][c];
    fatomic_add(&stats[c], s);
    fatomic_add(&stats[64 + c], q);
  }
}

// ---- GEMM: [n,K] @ [K,N] with 4 rows x 16 cols per thread.
// N=128 SPLIT: cols 0-63 = Wa -> bf16 out; cols 64-127 = Wb (+bias bb) -> f32 out.
template <int K, int N, int KT, bool SPLIT>
__global__ __launch_bounds__(256) void k_gemmv(
    const float* __restrict__ x, const float* __restrict__ Wa,
    const float* __restrict__ Wb, const float* __restrict__ bb,
    ushort* __restrict__ ob, float* __restrict__ of, int n) {
  constexpr int CS = N / 16;   // col segments
  constexpr int RS = 256 / CS; // row slots
  constexpr int TR = RS * 4;   // tile rows per block
  __shared__ float wS[KT * N];
  int tid = threadIdx.x;
  int cseg = tid % CS;
  int rslot = tid / CS;
  int baseRow = blockIdx.x * TR;

  float acc[4][16];
#pragma unroll
  for (int i = 0; i < 4; i++)
#pragma unroll
    for (int j = 0; j < 16; j++) acc[i][j] = 0.f;

  int rows[4];
  bool ok[4];
#pragma unroll
  for (int i = 0; i < 4; i++) {
    rows[i] = baseRow + rslot + i * RS;
    ok[i] = rows[i] < n;
  }

  for (int kt = 0; kt < K; kt += KT) {
    __syncthreads();
    for (int idx = tid; idx < KT * N / 4; idx += 256) {
      int kk = idx / (N / 4);
      int c4 = idx % (N / 4);
      const float* src = (SPLIT && c4 >= 16) ? Wb : Wa;
      int cc = SPLIT ? (c4 & 15) : c4;
      ((float4*)wS)[idx] = ((const float4*)(src + (size_t)(kt + kk) * 64))[cc];
    }
    __syncthreads();
#pragma unroll 2
    for (int k4 = 0; k4 < KT / 4; k4++) {
      float4 xv[4];
#pragma unroll
      for (int i = 0; i < 4; i++)
        xv[i] = ok[i] ? *(const float4*)(x + (size_t)rows[i] * K + kt + k4 * 4)
                      : make_float4(0.f, 0.f, 0.f, 0.f);
#pragma unroll
      for (int u = 0; u < 4; u++) {
        const float4* wr = (const float4*)(wS + (k4 * 4 + u) * N + cseg * 16);
        float4 w0 = wr[0], w1 = wr[1], w2 = wr[2], w3 = wr[3];
#pragma unroll
        for (int i = 0; i < 4; i++) {
          float ak = (u == 0) ? xv[i].x : (u == 1) ? xv[i].y : (u == 2) ? xv[i].z : xv[i].w;
          acc[i][0] = fmaf(ak, w0.x, acc[i][0]);
          acc[i][1] = fmaf(ak, w0.y, acc[i][1]);
          acc[i][2] = fmaf(ak, w0.z, acc[i][2]);
          acc[i][3] = fmaf(ak, w0.w, acc[i][3]);
          acc[i][4] = fmaf(ak, w1.x, acc[i][4]);
          acc[i][5] = fmaf(ak, w1.y, acc[i][5]);
          acc[i][6] = fmaf(ak, w1.z, acc[i][6]);
          acc[i][7] = fmaf(ak, w1.w, acc[i][7]);
          acc[i][8] = fmaf(ak, w2.x, acc[i][8]);
          acc[i][9] = fmaf(ak, w2.y, acc[i][9]);
          acc[i][10] = fmaf(ak, w2.z, acc[i][10]);
          acc[i][11] = fmaf(ak, w2.w, acc[i][11]);
          acc[i][12] = fmaf(ak, w3.x, acc[i][12]);
          acc[i][13] = fmaf(ak, w3.y, acc[i][13]);
          acc[i][14] = fmaf(ak, w3.z, acc[i][14]);
          acc[i][15] = fmaf(ak, w3.w, acc[i][15]);
        }
      }
    }
  }

  if (!SPLIT || cseg < CS / 2) {  // bf16 output half (or all, for N=64)
    int co = cseg * 16;
#pragma unroll
    for (int i = 0; i < 4; i++) {
      if (!ok[i]) continue;
      ushort* o = ob + (size_t)rows[i] * 64 + co;
      uint pk[8];
#pragma unroll
      for (int q = 0; q < 8; q++)
        pk[q] = (uint)f2bf(acc[i][2 * q]) | ((uint)f2bf(acc[i][2 * q + 1]) << 16);
      ((uint4*)o)[0] = make_uint4(pk[0], pk[1], pk[2], pk[3]);
      ((uint4*)o)[1] = make_uint4(pk[4], pk[5], pk[6], pk[7]);
    }
  } else {  // f32 residual half with bias
    int cs = cseg - CS / 2;
    float4 bv[4];
#pragma unroll
    for (int q = 0; q < 4; q++) bv[q] = ((const float4*)bb)[cs * 4 + q];
#pragma unroll
    for (int i = 0; i < 4; i++) {
      if (!ok[i]) continue;
      float* o = of + (size_t)rows[i] * 64 + cs * 16;
#pragma unroll
      for (int q = 0; q < 4; q++)
        ((float4*)o)[q] = make_float4(acc[i][q * 4 + 0] + bv[q].x, acc[i][q * 4 + 1] + bv[q].y,
                                      acc[i][q * 4 + 2] + bv[q].z, acc[i][q * 4 + 3] + bv[q].w);
    }
  }
}

// out = relu(g*(agg-mu)*rsqrt(var+eps)+beta) + res   (conv bias cancels in BN)
__global__ __launch_bounds__(256) void k_bnrelu(
    const float* __restrict__ agg, const float* __restrict__ res,
    const float* __restrict__ stats, const float* __restrict__ g,
    const float* __restrict__ beta, float* __restrict__ out, int n) {
  int idx = blockIdx.x * 256 + threadIdx.x;
  if (idx >= n * 16) return;
  int c4 = (idx & 15) * 4;
  float invN = 1.0f / (float)n;
  float4 a = ((const float4*)agg)[idx];
  float4 rr = ((const float4*)res)[idx];
  float av[4] = {a.x, a.y, a.z, a.w};
  float rv[4] = {rr.x, rr.y, rr.z, rr.w};
  float vo[4];
#pragma unroll
  for (int j = 0; j < 4; j++) {
    int c = c4 + j;
    float mu = stats[c] * invN;
    float var = stats[64 + c] * invN - mu * mu;
    float sc = g[c] * rsqrtf(var + BN_EPS);
    float v = (av[j] - mu) * sc + beta[c];
    vo[j] = fmaxf(v, 0.0f) + rv[j];
  }
  ((float4*)out)[idx] = make_float4(vo[0], vo[1], vo[2], vo[3]);
}

extern "C" void kernel_launch(void* const* d_in, const int* in_sizes, int n_in,
                              void* d_out, int out_size, void* d_ws, size_t ws_size,
                              hipStream_t stream) {
  const float* x = (const float*)d_in[0];
  const int* ei = (const int*)d_in[1];
  const float* ew = (const float*)d_in[2];
  const float* W1 = (const float*)d_in[3];
  const float* g1 = (const float*)d_in[5];
  const float* be1 = (const float*)d_in[6];
  const float* W2 = (const float*)d_in[7];
  const float* g2 = (const float*)d_in[9];
  const float* be2 = (const float*)d_in[10];
  const float* pW = (const float*)d_in[11];
  const float* pb = (const float*)d_in[12];

  int n = in_sizes[0] / 128;
  int e = in_sizes[1] / 2;
  const int* row = ei;      // source
  const int* col = ei + e;  // target

  // workspace layout
  float* ws = (float*)d_ws;
  float* dis = ws;                             // n
  int* ptr = (int*)(dis + n);                  // n+4
  int* cnt = ptr + n + 4;                      // n
  int* rank = cnt + n;                         // e
  int* bsum = rank + e;                        // 1024
  int2* spair = (int2*)(bsum + 1024);          // e int2
  ushort* hwb = (ushort*)(spair + e);          // n*64 bf16 (hw1, then hw2)
  float* bufR = (float*)(hwb + (size_t)n * 64);  // n*64 (residual)
  float* bufB = bufR + (size_t)n * 64;         // n*64 (agg)
  float* bufA = bufB + (size_t)n * 64;         // n*64 (h)
  float* stats = bufA + (size_t)n * 64;        // 128

  float* out = (float*)d_out;

  int nb_n = (n + 255) / 256;
  int nb_e = (e + 255) / 256;
  int nb_b = (n * 16 + 255) / 256;
  int nb_sc = (n + 1023) / 1024;
  int nb_g1 = (n + 127) / 128;
  int nb_g2 = (n + 255) / 256;

  // CSR build + gcn_norm
  hipMemsetAsync(cnt, 0, n * sizeof(int), stream);
  k_hist<<<nb_e, 256, 0, stream>>>(col, cnt, rank, e);
  k_scan_part<<<nb_sc, 256, 0, stream>>>(cnt, bsum, n);
  k_scan_mid<<<1, 1024, 0, stream>>>(bsum, nb_sc);
  k_scan_apply<<<nb_sc, 256, 0, stream>>>(cnt, ptr, bsum, n, e);
  k_fillcsr<<<nb_e, 256, 0, stream>>>(row, col, ew, ptr, rank, spair, e);
  k_degdis<<<nb_n, 256, 0, stream>>>(ptr, spair, dis, n);
  k_scale<<<nb_e, 256, 0, stream>>>(spair, dis, e);

  // layer 1: combined [x@W1 -> bf16 hwb | x@pW + pb -> f32 bufR]
  k_gemmv<128, 128, 64, true><<<nb_g1, 256, 0, stream>>>(x, W1, pW, pb, hwb, bufR, n);
  hipMemsetAsync(stats, 0, 128 * sizeof(float), stream);
  k_agg<<<2048, 256, 0, stream>>>(ptr, spair, dis, hwb, bufB, stats, n);
  k_bnrelu<<<nb_b, 256, 0, stream>>>(bufB, bufR, stats, g1, be1, bufA, n);

  // layer 2
  k_gemmv<64, 64, 64, false><<<nb_g2, 256, 0, stream>>>(bufA, W2, nullptr, nullptr, hwb, nullptr, n);
  hipMemsetAsync(stats, 0, 128 * sizeof(float), stream);
  k_agg<<<2048, 256, 0, stream>>>(ptr, spair, dis, hwb, bufB, stats, n);
  k_bnrelu<<<nb_b, 256, 0, stream>>>(bufB, bufA, stats, g2, be2, out, n);
}

// Round 8
// 475.959 us; speedup vs baseline: 6.4373x; 1.1339x over previous
//
#include <hip/hip_runtime.h>

static constexpr float BN_EPS = 1e-5f;
typedef unsigned int uint;
typedef unsigned short ushort;

__device__ __forceinline__ void fatomic_add(float* p, float v) {
  unsafeAtomicAdd(p, v);  // HW global_atomic_add_f32
}

__device__ __forceinline__ ushort f2bf(float f) {  // f32 -> bf16 RNE
  uint u = __float_as_uint(f);
  u += 0x7fffu + ((u >> 16) & 1u);
  return (ushort)(u >> 16);
}

__device__ __forceinline__ float4 bf4_decode(uint2 r) {
  return make_float4(__uint_as_float(r.x << 16), __uint_as_float(r.x & 0xffff0000u),
                     __uint_as_float(r.y << 16), __uint_as_float(r.y & 0xffff0000u));
}

// histogram keyed by col; stores each edge's arrival rank (for atomic-free fill)
__global__ void k_hist(const int* __restrict__ col, int* __restrict__ cnt,
                       int* __restrict__ rank, int e) {
  int i = blockIdx.x * 256 + threadIdx.x;
  if (i < e) rank[i] = atomicAdd(&cnt[col[i]], 1);
}

// ---- device-wide exclusive scan of cnt[n] (1024 elems/block) ----
__global__ __launch_bounds__(256) void k_scan_part(const int* __restrict__ cnt,
                                                   int* __restrict__ bsum, int n) {
  __shared__ int sm[256];
  int t = threadIdx.x;
  int base = blockIdx.x * 1024 + t * 4;
  int s = 0;
#pragma unroll
  for (int j = 0; j < 4; j++) {
    int i = base + j;
    if (i < n) s += cnt[i];
  }
  sm[t] = s;
  __syncthreads();
  for (int off = 128; off > 0; off >>= 1) {
    if (t < off) sm[t] += sm[t + off];
    __syncthreads();
  }
  if (t == 0) bsum[blockIdx.x] = sm[0];
}

__global__ __launch_bounds__(1024) void k_scan_mid(int* __restrict__ bsum, int nb) {
  __shared__ int sm[1024];
  int t = threadIdx.x;
  int v = (t < nb) ? bsum[t] : 0;
  sm[t] = v;
  __syncthreads();
  for (int off = 1; off < 1024; off <<= 1) {
    int o = (t >= off) ? sm[t - off] : 0;
    __syncthreads();
    sm[t] += o;
    __syncthreads();
  }
  if (t < nb) bsum[t] = sm[t] - v;  // exclusive block offsets
}

__global__ __launch_bounds__(256) void k_scan_apply(const int* __restrict__ cnt,
                                                    int* __restrict__ ptr,
                                                    const int* __restrict__ bsum,
                                                    int n, int e) {
  __shared__ int sm[256];
  int t = threadIdx.x;
  int base = blockIdx.x * 1024 + t * 4;
  int v[4];
  int s = 0;
#pragma unroll
  for (int j = 0; j < 4; j++) {
    int i = base + j;
    v[j] = (i < n) ? cnt[i] : 0;
    s += v[j];
  }
  sm[t] = s;
  __syncthreads();
  for (int off = 1; off < 256; off <<= 1) {
    int o = (t >= off) ? sm[t - off] : 0;
    __syncthreads();
    sm[t] += o;
    __syncthreads();
  }
  int run = bsum[blockIdx.x] + sm[t] - s;
#pragma unroll
  for (int j = 0; j < 4; j++) {
    int i = base + j;
    if (i < n) {
      ptr[i] = run;
      run += v[j];
    }
  }
  if (blockIdx.x == 0 && t == 0) ptr[n] = e;
}

// atomic-free CSR fill: slot = ptr[col] + rank
__global__ void k_fillcsr(const int* __restrict__ row, const int* __restrict__ col,
                          const float* __restrict__ ew, const int* __restrict__ ptr,
                          const int* __restrict__ rank, int2* __restrict__ spair, int e) {
  int i = blockIdx.x * 256 + threadIdx.x;
  if (i >= e) return;
  int p = ptr[col[i]] + rank[i];
  spair[p] = make_int2(row[i], __float_as_int(ew[i]));
}

// per-node: deg = 1 (self-loop) + segment-sum of ew; dis = rsqrt(deg). No atomics.
__global__ void k_degdis(const int* __restrict__ ptr, const int2* __restrict__ spair,
                         float* __restrict__ dis, int n) {
  int v = blockIdx.x * 256 + threadIdx.x;
  if (v >= n) return;
  int b = ptr[v], en = ptr[v + 1];
  float s = 1.0f;
  for (int j = b; j < en; j++) s += __int_as_float(spair[j].y);
  dis[v] = rsqrtf(s);
}

// fold dis[row] into stored edge weight (dis[col] applied in k_agg)
__global__ void k_scale(int2* __restrict__ spair, const float* __restrict__ dis, int e) {
  int i = blockIdx.x * 256 + threadIdx.x;
  if (i >= e) return;
  int2 m = spair[i];
  spair[i] = make_int2(m.x, __float_as_int(__int_as_float(m.y) * dis[m.x]));
}

// ---- aggregation v3 + fused BN stats.
// One NODE per 16-lane group (4 nodes/wave). Edges consumed in 4-edge aligned
// chunks; depth-2 chunk pipeline keeps 4 row-gathers + 2 meta int4 loads in
// flight per group (16 line-misses/wave) while computing the previous chunk.
// Head/tail edges masked: weight 0, row -> v (L1-hot line, no wasted miss).
__global__ __launch_bounds__(256) void k_agg(
    const int* __restrict__ ptr, const int2* __restrict__ spair,
    const float* __restrict__ dis, const ushort* __restrict__ hwb,
    float* __restrict__ agg, float* __restrict__ stats, int n) {
  int lane = threadIdx.x & 63;
  int grp = lane >> 4;
  int li = lane & 15;
  int wid = blockIdx.x * 4 + (threadIdx.x >> 6);
  int nw = gridDim.x * 4;
  float st_s[4] = {0.f, 0.f, 0.f, 0.f};
  float st_q[4] = {0.f, 0.f, 0.f, 0.f};

  for (int vb = wid * 4; vb < n; vb += nw * 4) {
    int v = vb + grp;
    bool on = v < n;
    float4 acc = make_float4(0.f, 0.f, 0.f, 0.f);
    float d = 0.f;
    int beg = 0, end = 0;
    if (on) {
      beg = ptr[v];
      end = ptr[v + 1];
      d = dis[v];
      uint2 rs = *(const uint2*)(hwb + (size_t)v * 64 + li * 4);
      float4 f = bf4_decode(rs);
      acc = make_float4(d * f.x, d * f.y, d * f.z, d * f.w);  // self-loop (1 of 2 dis)
    }
    if (on && beg < end) {
      const int4* sp = (const int4*)spair;
      int jc = beg & ~3;           // 4-edge aligned chunk start
      int h = jc >> 1;             // int4 index of chunk
      int nch = (end - jc + 3) >> 2;
      int4 a0 = sp[h], a1 = sp[h + 1];  // meta chunk 0
      int4 b0, b1;                       // meta chunk c+1 (guarded use)
      if (nch > 1) { b0 = sp[h + 2]; b1 = sp[h + 3]; }
      float wC[4];
      uint2 gC[4];
      {
        int rr[4] = {a0.x, a0.z, a1.x, a1.z};
        int wi[4] = {a0.y, a0.w, a1.y, a1.w};
#pragma unroll
        for (int k = 0; k < 4; k++) {
          int idx = jc + k;
          bool okk = (idx >= beg) && (idx < end);
          int r = okk ? rr[k] : v;
          wC[k] = okk ? __int_as_float(wi[k]) : 0.f;
          gC[k] = *(const uint2*)(hwb + (size_t)r * 64 + li * 4);
        }
      }
      for (int c = 0; c < nch; c++) {
        float wN[4];
        uint2 gN[4];
        if (c + 1 < nch) {  // extract meta(c+1), issue its gathers
          int jn = jc + 4;
          int rr[4] = {b0.x, b0.z, b1.x, b1.z};
          int wi[4] = {b0.y, b0.w, b1.y, b1.w};
#pragma unroll
          for (int k = 0; k < 4; k++) {
            bool okk = (jn + k) < end;
            int r = okk ? rr[k] : v;
            wN[k] = okk ? __int_as_float(wi[k]) : 0.f;
            gN[k] = *(const uint2*)(hwb + (size_t)r * 64 + li * 4);
          }
        }
        if (c + 2 < nch) {  // prefetch meta(c+2)
          b0 = sp[h + 2 * (c + 2)];
          b1 = sp[h + 2 * (c + 2) + 1];
        }
#pragma unroll
        for (int k = 0; k < 4; k++) {  // compute chunk c
          float4 f = bf4_decode(gC[k]);
          acc.x = fmaf(wC[k], f.x, acc.x);
          acc.y = fmaf(wC[k], f.y, acc.y);
          acc.z = fmaf(wC[k], f.z, acc.z);
          acc.w = fmaf(wC[k], f.w, acc.w);
        }
        if (c + 1 < nch) {
#pragma unroll
          for (int k = 0; k < 4; k++) { gC[k] = gN[k]; wC[k] = wN[k]; }
        }
        jc += 4;
      }
    }
    if (on) {
      acc.x *= d; acc.y *= d; acc.z *= d; acc.w *= d;  // 2nd dis factor
      *(float4*)(agg + (size_t)v * 64 + li * 4) = acc;
      st_s[0] += acc.x; st_s[1] += acc.y; st_s[2] += acc.z; st_s[3] += acc.w;
      st_q[0] = fmaf(acc.x, acc.x, st_q[0]);
      st_q[1] = fmaf(acc.y, acc.y, st_q[1]);
      st_q[2] = fmaf(acc.z, acc.z, st_q[2]);
      st_q[3] = fmaf(acc.w, acc.w, st_q[3]);
    }
  }

  // cross-group reduce (channels of lane l == channels of lane l^16, l^32)
#pragma unroll
  for (int j = 0; j < 4; j++) {
    st_s[j] += __shfl_xor(st_s[j], 16);
    st_s[j] += __shfl_xor(st_s[j], 32);
    st_q[j] += __shfl_xor(st_q[j], 16);
    st_q[j] += __shfl_xor(st_q[j], 32);
  }
  __shared__ float rs[4][64];
  __shared__ float rq[4][64];
  int wv = threadIdx.x >> 6;
  if (grp == 0) {
#pragma unroll
    for (int j = 0; j < 4; j++) {
      rs[wv][li * 4 + j] = st_s[j];
      rq[wv][li * 4 + j] = st_q[j];
    }
  }
  __syncthreads();
  if (threadIdx.x < 64) {
    int c = threadIdx.x;
    float s = rs[0][c] + rs[1][c] + rs[2][c] + rs[3][c];
    float q = rq[0][c] + rq[1][c] + rq[2][c] + rq[3][c];
    fatomic_add(&stats[c], s);
    fatomic_add(&stats[64 + c], q);
  }
}

// ---- GEMM: [n,K] @ [K,N] with 4 rows x 16 cols per thread.
// N=128 SPLIT: cols 0-63 = Wa -> bf16 out; cols 64-127 = Wb (+bias bb) -> f32 out.
template <int K, int N, int KT, bool SPLIT>
__global__ __launch_bounds__(256) void k_gemmv(
    const float* __restrict__ x, const float* __restrict__ Wa,
    const float* __restrict__ Wb, const float* __restrict__ bb,
    ushort* __restrict__ ob, float* __restrict__ of, int n) {
  constexpr int CS = N / 16;   // col segments
  constexpr int RS = 256 / CS; // row slots
  constexpr int TR = RS * 4;   // tile rows per block
  __shared__ float wS[KT * N];
  int tid = threadIdx.x;
  int cseg = tid % CS;
  int rslot = tid / CS;
  int baseRow = blockIdx.x * TR;

  float acc[4][16];
#pragma unroll
  for (int i = 0; i < 4; i++)
#pragma unroll
    for (int j = 0; j < 16; j++) acc[i][j] = 0.f;

  int rows[4];
  bool ok[4];
#pragma unroll
  for (int i = 0; i < 4; i++) {
    rows[i] = baseRow + rslot + i * RS;
    ok[i] = rows[i] < n;
  }

  for (int kt = 0; kt < K; kt += KT) {
    __syncthreads();
    for (int idx = tid; idx < KT * N / 4; idx += 256) {
      int kk = idx / (N / 4);
      int c4 = idx % (N / 4);
      const float* src = (SPLIT && c4 >= 16) ? Wb : Wa;
      int cc = SPLIT ? (c4 & 15) : c4;
      ((float4*)wS)[idx] = ((const float4*)(src + (size_t)(kt + kk) * 64))[cc];
    }
    __syncthreads();
#pragma unroll 2
    for (int k4 = 0; k4 < KT / 4; k4++) {
      float4 xv[4];
#pragma unroll
      for (int i = 0; i < 4; i++)
        xv[i] = ok[i] ? *(const float4*)(x + (size_t)rows[i] * K + kt + k4 * 4)
                      : make_float4(0.f, 0.f, 0.f, 0.f);
#pragma unroll
      for (int u = 0; u < 4; u++) {
        const float4* wr = (const float4*)(wS + (k4 * 4 + u) * N + cseg * 16);
        float4 w0 = wr[0], w1 = wr[1], w2 = wr[2], w3 = wr[3];
#pragma unroll
        for (int i = 0; i < 4; i++) {
          float ak = (u == 0) ? xv[i].x : (u == 1) ? xv[i].y : (u == 2) ? xv[i].z : xv[i].w;
          acc[i][0] = fmaf(ak, w0.x, acc[i][0]);
          acc[i][1] = fmaf(ak, w0.y, acc[i][1]);
          acc[i][2] = fmaf(ak, w0.z, acc[i][2]);
          acc[i][3] = fmaf(ak, w0.w, acc[i][3]);
          acc[i][4] = fmaf(ak, w1.x, acc[i][4]);
          acc[i][5] = fmaf(ak, w1.y, acc[i][5]);
          acc[i][6] = fmaf(ak, w1.z, acc[i][6]);
          acc[i][7] = fmaf(ak, w1.w, acc[i][7]);
          acc[i][8] = fmaf(ak, w2.x, acc[i][8]);
          acc[i][9] = fmaf(ak, w2.y, acc[i][9]);
          acc[i][10] = fmaf(ak, w2.z, acc[i][10]);
          acc[i][11] = fmaf(ak, w2.w, acc[i][11]);
          acc[i][12] = fmaf(ak, w3.x, acc[i][12]);
          acc[i][13] = fmaf(ak, w3.y, acc[i][13]);
          acc[i][14] = fmaf(ak, w3.z, acc[i][14]);
          acc[i][15] = fmaf(ak, w3.w, acc[i][15]);
        }
      }
    }
  }

  if (!SPLIT || cseg < CS / 2) {  // bf16 output half (or all, for N=64)
    int co = cseg * 16;
#pragma unroll
    for (int i = 0; i < 4; i++) {
      if (!ok[i]) continue;
      ushort* o = ob + (size_t)rows[i] * 64 + co;
      uint pk[8];
#pragma unroll
      for (int q = 0; q < 8; q++)
        pk[q] = (uint)f2bf(acc[i][2 * q]) | ((uint)f2bf(acc[i][2 * q + 1]) << 16);
      ((uint4*)o)[0] = make_uint4(pk[0], pk[1], pk[2], pk[3]);
      ((uint4*)o)[1] = make_uint4(pk[4], pk[5], pk[6], pk[7]);
    }
  } else {  // f32 residual half with bias
    int cs = cseg - CS / 2;
    float4 bv[4];
#pragma unroll
    for (int q = 0; q < 4; q++) bv[q] = ((const float4*)bb)[cs * 4 + q];
#pragma unroll
    for (int i = 0; i < 4; i++) {
      if (!ok[i]) continue;
      float* o = of + (size_t)rows[i] * 64 + cs * 16;
#pragma unroll
      for (int q = 0; q < 4; q++)
        ((float4*)o)[q] = make_float4(acc[i][q * 4 + 0] + bv[q].x, acc[i][q * 4 + 1] + bv[q].y,
                                      acc[i][q * 4 + 2] + bv[q].z, acc[i][q * 4 + 3] + bv[q].w);
    }
  }
}

// out = relu(g*(agg-mu)*rsqrt(var+eps)+beta) + res   (conv bias cancels in BN)
__global__ __launch_bounds__(256) void k_bnrelu(
    const float* __restrict__ agg, const float* __restrict__ res,
    const float* __restrict__ stats, const float* __restrict__ g,
    const float* __restrict__ beta, float* __restrict__ out, int n) {
  int idx = blockIdx.x * 256 + threadIdx.x;
  if (idx >= n * 16) return;
  int c4 = (idx & 15) * 4;
  float invN = 1.0f / (float)n;
  float4 a = ((const float4*)agg)[idx];
  float4 rr = ((const float4*)res)[idx];
  float av[4] = {a.x, a.y, a.z, a.w};
  float rv[4] = {rr.x, rr.y, rr.z, rr.w};
  float vo[4];
#pragma unroll
  for (int j = 0; j < 4; j++) {
    int c = c4 + j;
    float mu = stats[c] * invN;
    float var = stats[64 + c] * invN - mu * mu;
    float sc = g[c] * rsqrtf(var + BN_EPS);
    float v = (av[j] - mu) * sc + beta[c];
    vo[j] = fmaxf(v, 0.0f) + rv[j];
  }
  ((float4*)out)[idx] = make_float4(vo[0], vo[1], vo[2], vo[3]);
}

extern "C" void kernel_launch(void* const* d_in, const int* in_sizes, int n_in,
                              void* d_out, int out_size, void* d_ws, size_t ws_size,
                              hipStream_t stream) {
  const float* x = (const float*)d_in[0];
  const int* ei = (const int*)d_in[1];
  const float* ew = (const float*)d_in[2];
  const float* W1 = (const float*)d_in[3];
  const float* g1 = (const float*)d_in[5];
  const float* be1 = (const float*)d_in[6];
  const float* W2 = (const float*)d_in[7];
  const float* g2 = (const float*)d_in[9];
  const float* be2 = (const float*)d_in[10];
  const float* pW = (const float*)d_in[11];
  const float* pb = (const float*)d_in[12];

  int n = in_sizes[0] / 128;
  int e = in_sizes[1] / 2;
  const int* row = ei;      // source
  const int* col = ei + e;  // target

  // workspace layout (spair padded by 16 int2: chunked k_agg may over-READ
  // up to 3 entries past e; masked before use)
  float* ws = (float*)d_ws;
  float* dis = ws;                             // n
  int* ptr = (int*)(dis + n);                  // n+4
  int* cnt = ptr + n + 4;                      // n
  int* rank = cnt + n;                         // e
  int* bsum = rank + e;                        // 1024
  int2* spair = (int2*)(bsum + 1024);          // e int2 (+16 pad)
  ushort* hwb = (ushort*)(spair + e + 16);     // n*64 bf16 (hw1, then hw2)
  float* bufR = (float*)(hwb + (size_t)n * 64);  // n*64 (residual)
  float* bufB = bufR + (size_t)n * 64;         // n*64 (agg)
  float* bufA = bufB + (size_t)n * 64;         // n*64 (h)
  float* stats = bufA + (size_t)n * 64;        // 128

  float* out = (float*)d_out;

  int nb_n = (n + 255) / 256;
  int nb_e = (e + 255) / 256;
  int nb_b = (n * 16 + 255) / 256;
  int nb_sc = (n + 1023) / 1024;
  int nb_g1 = (n + 127) / 128;
  int nb_g2 = (n + 255) / 256;

  // CSR build + gcn_norm
  hipMemsetAsync(cnt, 0, n * sizeof(int), stream);
  k_hist<<<nb_e, 256, 0, stream>>>(col, cnt, rank, e);
  k_scan_part<<<nb_sc, 256, 0, stream>>>(cnt, bsum, n);
  k_scan_mid<<<1, 1024, 0, stream>>>(bsum, nb_sc);
  k_scan_apply<<<nb_sc, 256, 0, stream>>>(cnt, ptr, bsum, n, e);
  k_fillcsr<<<nb_e, 256, 0, stream>>>(row, col, ew, ptr, rank, spair, e);
  k_degdis<<<nb_n, 256, 0, stream>>>(ptr, spair, dis, n);
  k_scale<<<nb_e, 256, 0, stream>>>(spair, dis, e);

  // layer 1: combined [x@W1 -> bf16 hwb | x@pW + pb -> f32 bufR]
  k_gemmv<128, 128, 64, true><<<nb_g1, 256, 0, stream>>>(x, W1, pW, pb, hwb, bufR, n);
  hipMemsetAsync(stats, 0, 128 * sizeof(float), stream);
  k_agg<<<2048, 256, 0, stream>>>(ptr, spair, dis, hwb, bufB, stats, n);
  k_bnrelu<<<nb_b, 256, 0, stream>>>(bufB, bufR, stats, g1, be1, bufA, n);

  // layer 2
  k_gemmv<64, 64, 64, false><<<nb_g2, 256, 0, stream>>>(bufA, W2, nullptr, nullptr, hwb, nullptr, n);
  hipMemsetAsync(stats, 0, 128 * sizeof(float), stream);
  k_agg<<<2048, 256, 0, stream>>>(ptr, spair, dis, hwb, bufB, stats, n);
  k_bnrelu<<<nb_b, 256, 0, stream>>>(bufB, bufA, stats, g2, be2, out, n);
}